// Round 4
// baseline (272.847 us; speedup 1.0000x reference)
//
#include <hip/hip_runtime.h>
#include <cmath>
#include <cstdint>

#define NLEVELS 16
#define LOG2T 19
#define TSIZE (1u << LOG2T)

struct ResTable { float r[NLEVELS]; };

// ---- ws layout (bytes) ----
#define WS_TBL    0u                      // 16*TSIZE*4  = 33,554,432  packed bf16 table
#define WS_EMB    33554432u               // 8*N*8       = 16,777,216  packed bf16 emb
#define WS_WOUTT  50331648u               // 64*16*4     = 4,096       xyz_wout^T
#define WS_W1T    50335744u               // 64*64*4     = 16,384      rgb_w1^T
#define WS_RWOUTT 50352128u               // 64*3*4      = 768         rgb_wout^T
#define WS_TOTAL  50352896u

__device__ inline uint16_t f32_to_bf16_rne(float f) {
    uint32_t u = __float_as_uint(f);
    uint32_t rounding = 0x7fffu + ((u >> 16) & 1u);
    return (uint16_t)((u + rounding) >> 16);
}

// ---------------------------------------------------------------------------
// Prep 0: f32 table (L,T,2) -> packed bf16 (L,T) uint32
// ---------------------------------------------------------------------------
__global__ __launch_bounds__(256) void conv_table(
    const float* __restrict__ t, uint32_t* __restrict__ o, int n_pairs)
{
    int i = blockIdx.x * blockDim.x + threadIdx.x;
    if (i >= n_pairs) return;
    float2 v = *reinterpret_cast<const float2*>(t + 2 * (size_t)i);
    o[i] = (uint32_t)f32_to_bf16_rne(v.x) | ((uint32_t)f32_to_bf16_rne(v.y) << 16);
}

// ---------------------------------------------------------------------------
// Prep 1: transpose the column-accessed weight matrices into ws (f32).
//   woutT[j*16+o]  = xyz_wout[o*64+j]   (1024)
//   w1T[j*64+jj]   = rgb_w1[jj*64+j]    (4096)
//   rwoutT[j*3+o]  = rgb_wout[o*64+j]   (192)
// ---------------------------------------------------------------------------
__global__ __launch_bounds__(256) void prep_weights(
    const float* __restrict__ xyz_wout, const float* __restrict__ rgb_w1,
    const float* __restrict__ rgb_wout, float* __restrict__ woutT,
    float* __restrict__ w1T, float* __restrict__ rwoutT)
{
    int t = blockIdx.x * blockDim.x + threadIdx.x;
    if (t < 1024) {
        int j = t >> 4, o = t & 15;
        woutT[t] = xyz_wout[o * 64 + j];
    } else if (t < 5120) {
        int e = t - 1024; int j = e >> 6, jj = e & 63;
        w1T[e] = rgb_w1[jj * 64 + j];
    } else if (t < 5312) {
        int e = t - 5120; int j = e / 3, o = e % 3;
        rwoutT[e] = rgb_wout[o * 64 + j];
    }
}

// ---------------------------------------------------------------------------
// Kernel 1: hash encode, 2 levels (slot, slot+8) per thread.
// blockIdx&7 = slot -> XCD-pinned: levels {s, s+8} footprint <= 4MB = one L2.
// Output embT[slot][point] = uint2{pack(l=s), pack(l=s+8)}.
// ---------------------------------------------------------------------------
__global__ __launch_bounds__(256) void ngp_encode(
    const float* __restrict__ x, const uint32_t* __restrict__ tbl,
    uint2* __restrict__ embT, ResTable res, int n)
{
    int slot  = blockIdx.x & 7;
    int i = (blockIdx.x >> 3) * 256 + threadIdx.x;
    if (i >= n) return;

    float xn0 = x[3 * i + 0] + 0.5f;
    float xn1 = x[3 * i + 1] + 0.5f;
    float xn2 = x[3 * i + 2] + 0.5f;

    uint32_t idx[16];
    float    wg[16];
    #pragma unroll
    for (int ll = 0; ll < 2; ++ll) {
        int l = slot + ll * 8;
        float r  = res.r[l];
        float p0 = xn0 * r, p1 = xn1 * r, p2 = xn2 * r;
        float f0 = floorf(p0), f1 = floorf(p1), f2 = floorf(p2);
        float fr0 = p0 - f0, fr1 = p1 - f1, fr2 = p2 - f2;
        uint32_t xi0 = (uint32_t)f0, xi1 = (uint32_t)f1, xi2 = (uint32_t)f2;
        uint32_t hx0 = xi0,               hx1 = xi0 + 1u;
        uint32_t hy0 = xi1 * 2654435761u, hy1 = (xi1 + 1u) * 2654435761u;
        uint32_t hz0 = xi2 * 805459861u,  hz1 = (xi2 + 1u) * 805459861u;
        #pragma unroll
        for (int c = 0; c < 8; ++c) {
            uint32_t hx = (c & 4) ? hx1 : hx0;
            uint32_t hy = (c & 2) ? hy1 : hy0;
            uint32_t hz = (c & 1) ? hz1 : hz0;
            idx[ll * 8 + c] = (hx ^ hy ^ hz) & (TSIZE - 1u);
            float wx = (c & 4) ? fr0 : 1.f - fr0;
            float wy = (c & 2) ? fr1 : 1.f - fr1;
            float wz = (c & 1) ? fr2 : 1.f - fr2;
            wg[ll * 8 + c] = wx * wy * wz;
        }
    }
    // all 16 loads in flight before any use
    uint32_t val[16];
    #pragma unroll
    for (int ll = 0; ll < 2; ++ll) {
        const uint32_t* tl = tbl + (size_t)(slot + ll * 8) * (size_t)TSIZE;
        #pragma unroll
        for (int c = 0; c < 8; ++c) val[ll * 8 + c] = tl[idx[ll * 8 + c]];
    }
    uint2 o;
    #pragma unroll
    for (int ll = 0; ll < 2; ++ll) {
        float a0 = 0.f, a1 = 0.f;
        #pragma unroll
        for (int c = 0; c < 8; ++c) {
            uint32_t pv = val[ll * 8 + c];
            float w = wg[ll * 8 + c];
            a0 = fmaf(w, __uint_as_float(pv << 16), a0);
            a1 = fmaf(w, __uint_as_float(pv & 0xffff0000u), a1);
        }
        uint32_t pk = (uint32_t)f32_to_bf16_rne(a0) |
                      ((uint32_t)f32_to_bf16_rne(a1) << 16);
        if (ll == 0) o.x = pk; else o.y = pk;
    }
    embT[(size_t)slot * n + i] = o;
}

// ---------------------------------------------------------------------------
// Kernel 2: SH + MLPs, streaming accumulators (peak live ~110 VGPR).
// ---------------------------------------------------------------------------
__global__ __launch_bounds__(256, 4) void ngp_mlp(
    const uint2* __restrict__ embT,     // (8, N) packed bf16
    const float* __restrict__ d,        // (N,3)
    const float* __restrict__ xyz_w0,   // (64,32) row-major
    const float* __restrict__ woutT,    // (64,16)
    const float* __restrict__ rgb_w0,   // (64,32) row-major
    const float* __restrict__ w1T,      // (64,64)
    const float* __restrict__ rwoutT,   // (64,3)
    float* __restrict__ out, int n)
{
    int i = blockIdx.x * blockDim.x + threadIdx.x;
    if (i >= n) return;

    float emb[32];
    #pragma unroll
    for (int s = 0; s < 8; ++s) {
        uint2 w = embT[(size_t)s * n + i];
        emb[2 * s + 0]        = __uint_as_float(w.x << 16);
        emb[2 * s + 1]        = __uint_as_float(w.x & 0xffff0000u);
        emb[2 * (s + 8) + 0]  = __uint_as_float(w.y << 16);
        emb[2 * (s + 8) + 1]  = __uint_as_float(w.y & 0xffff0000u);
    }

    // xyz MLP 32 -> 64(ReLU) -> 16, h1[j] consumed immediately
    float hh[16];
    #pragma unroll
    for (int o = 0; o < 16; ++o) hh[o] = 0.f;
    #pragma unroll
    for (int j = 0; j < 64; ++j) {
        float s = 0.f;
        #pragma unroll
        for (int k = 0; k < 32; ++k) s = fmaf(emb[k], xyz_w0[j * 32 + k], s);
        s = fmaxf(s, 0.f);
        #pragma unroll
        for (int o = 0; o < 16; ++o) hh[o] = fmaf(s, woutT[j * 16 + o], hh[o]);
    }
    out[i] = expf(hh[0]);   // sigma

    // SH degree-4
    float dx = d[3 * i + 0], dy = d[3 * i + 1], dz = d[3 * i + 2];
    float inv = rsqrtf(dx * dx + dy * dy + dz * dz);
    float X = dx * inv, Y = dy * inv, Z = dz * inv;
    float xx = X * X, yy = Y * Y, zz = Z * Z;
    float xy = X * Y, yz = Y * Z, xz = X * Z;

    float f[32];
    f[0]  = 0.28209479177387814f;
    f[1]  = -0.4886025119029199f * Y;
    f[2]  =  0.4886025119029199f * Z;
    f[3]  = -0.4886025119029199f * X;
    f[4]  =  1.0925484305920792f * xy;
    f[5]  = -1.0925484305920792f * yz;
    f[6]  =  0.31539156525252005f * (3.0f * zz - 1.0f);
    f[7]  = -1.0925484305920792f * xz;
    f[8]  =  0.5462742152960396f * (xx - yy);
    f[9]  = -0.5900435899266435f * Y * (3.0f * xx - yy);
    f[10] =  2.890611442640554f * xy * Z;
    f[11] = -0.4570457994644658f * Y * (4.0f * zz - xx - yy);
    f[12] =  0.3731763325901154f * Z * (2.0f * zz - 3.0f * xx - 3.0f * yy);
    f[13] = -0.4570457994644658f * X * (4.0f * zz - xx - yy);
    f[14] =  1.445305721320277f * Z * (xx - yy);
    f[15] = -0.5900435899266435f * X * (xx - 3.0f * yy);
    #pragma unroll
    for (int o = 0; o < 16; ++o) f[16 + o] = hh[o];

    // rgb MLP 32 -> 64(ReLU) -> 64(ReLU) -> 3(sigmoid)
    // b1[j] consumed immediately into b2 accumulators (k-outer via w1T)
    float b2[64];
    #pragma unroll
    for (int j = 0; j < 64; ++j) b2[j] = 0.f;
    #pragma unroll
    for (int j = 0; j < 64; ++j) {
        float s = 0.f;
        #pragma unroll
        for (int k = 0; k < 32; ++k) s = fmaf(f[k], rgb_w0[j * 32 + k], s);
        s = fmaxf(s, 0.f);
        #pragma unroll
        for (int jj = 0; jj < 64; ++jj) b2[jj] = fmaf(s, w1T[j * 64 + jj], b2[jj]);
    }
    float o3[3] = {0.f, 0.f, 0.f};
    #pragma unroll
    for (int j = 0; j < 64; ++j) {
        float s = fmaxf(b2[j], 0.f);
        #pragma unroll
        for (int o = 0; o < 3; ++o) o3[o] = fmaf(s, rwoutT[j * 3 + o], o3[o]);
    }
    #pragma unroll
    for (int o = 0; o < 3; ++o)
        out[n + 3 * i + o] = 1.0f / (1.0f + expf(-o3[o]));
}

// ---------------------------------------------------------------------------
// Mid fallback (ws >= 33.5MB only): round-3 fused bf16 kernel.
// ---------------------------------------------------------------------------
__global__ __launch_bounds__(256) void ngp_fused_bf16(
    const float* __restrict__ x, const float* __restrict__ d,
    const uint32_t* __restrict__ tbl,
    const float* __restrict__ xyz_w0, const float* __restrict__ xyz_wout,
    const float* __restrict__ rgb_w0, const float* __restrict__ rgb_w1,
    const float* __restrict__ rgb_wout, float* __restrict__ out,
    ResTable res, int n)
{
    int i = blockIdx.x * blockDim.x + threadIdx.x;
    if (i >= n) return;

    float xn0 = x[3 * i + 0] + 0.5f;
    float xn1 = x[3 * i + 1] + 0.5f;
    float xn2 = x[3 * i + 2] + 0.5f;

    float emb[NLEVELS * 2];
    #pragma unroll
    for (int b = 0; b < 4; ++b) {
        uint32_t idx[32]; float wg[32];
        #pragma unroll
        for (int ll = 0; ll < 4; ++ll) {
            int l = b * 4 + ll;
            float r  = res.r[l];
            float p0 = xn0 * r, p1 = xn1 * r, p2 = xn2 * r;
            float f0 = floorf(p0), f1 = floorf(p1), f2 = floorf(p2);
            float fr0 = p0 - f0, fr1 = p1 - f1, fr2 = p2 - f2;
            uint32_t xi0 = (uint32_t)f0, xi1 = (uint32_t)f1, xi2 = (uint32_t)f2;
            uint32_t hx0 = xi0,               hx1 = xi0 + 1u;
            uint32_t hy0 = xi1 * 2654435761u, hy1 = (xi1 + 1u) * 2654435761u;
            uint32_t hz0 = xi2 * 805459861u,  hz1 = (xi2 + 1u) * 805459861u;
            #pragma unroll
            for (int c = 0; c < 8; ++c) {
                uint32_t hx = (c & 4) ? hx1 : hx0;
                uint32_t hy = (c & 2) ? hy1 : hy0;
                uint32_t hz = (c & 1) ? hz1 : hz0;
                idx[ll * 8 + c] = (hx ^ hy ^ hz) & (TSIZE - 1u);
                float wx = (c & 4) ? fr0 : 1.f - fr0;
                float wy = (c & 2) ? fr1 : 1.f - fr1;
                float wz = (c & 1) ? fr2 : 1.f - fr2;
                wg[ll * 8 + c] = wx * wy * wz;
            }
        }
        uint32_t val[32];
        #pragma unroll
        for (int ll = 0; ll < 4; ++ll) {
            const uint32_t* tl = tbl + (size_t)(b * 4 + ll) * (size_t)TSIZE;
            #pragma unroll
            for (int c = 0; c < 8; ++c) val[ll * 8 + c] = tl[idx[ll * 8 + c]];
        }
        #pragma unroll
        for (int ll = 0; ll < 4; ++ll) {
            float a0 = 0.f, a1 = 0.f;
            #pragma unroll
            for (int c = 0; c < 8; ++c) {
                uint32_t pv = val[ll * 8 + c];
                float w = wg[ll * 8 + c];
                a0 = fmaf(w, __uint_as_float(pv << 16), a0);
                a1 = fmaf(w, __uint_as_float(pv & 0xffff0000u), a1);
            }
            emb[2 * (b * 4 + ll)]     = a0;
            emb[2 * (b * 4 + ll) + 1] = a1;
        }
    }

    float h1[64];
    #pragma unroll
    for (int j = 0; j < 64; ++j) {
        float s = 0.f;
        #pragma unroll
        for (int k = 0; k < 32; ++k) s = fmaf(emb[k], xyz_w0[j * 32 + k], s);
        h1[j] = fmaxf(s, 0.f);
    }
    float hh[16];
    #pragma unroll
    for (int o = 0; o < 16; ++o) {
        float s = 0.f;
        #pragma unroll
        for (int k = 0; k < 64; ++k) s = fmaf(h1[k], xyz_wout[o * 64 + k], s);
        hh[o] = s;
    }
    out[i] = expf(hh[0]);

    float dx = d[3 * i + 0], dy = d[3 * i + 1], dz = d[3 * i + 2];
    float inv = rsqrtf(dx * dx + dy * dy + dz * dz);
    float X = dx * inv, Y = dy * inv, Z = dz * inv;
    float xx = X * X, yy = Y * Y, zz = Z * Z;
    float xy = X * Y, yz = Y * Z, xz = X * Z;

    float f[32];
    f[0]  = 0.28209479177387814f;
    f[1]  = -0.4886025119029199f * Y;
    f[2]  =  0.4886025119029199f * Z;
    f[3]  = -0.4886025119029199f * X;
    f[4]  =  1.0925484305920792f * xy;
    f[5]  = -1.0925484305920792f * yz;
    f[6]  =  0.31539156525252005f * (3.0f * zz - 1.0f);
    f[7]  = -1.0925484305920792f * xz;
    f[8]  =  0.5462742152960396f * (xx - yy);
    f[9]  = -0.5900435899266435f * Y * (3.0f * xx - yy);
    f[10] =  2.890611442640554f * xy * Z;
    f[11] = -0.4570457994644658f * Y * (4.0f * zz - xx - yy);
    f[12] =  0.3731763325901154f * Z * (2.0f * zz - 3.0f * xx - 3.0f * yy);
    f[13] = -0.4570457994644658f * X * (4.0f * zz - xx - yy);
    f[14] =  1.445305721320277f * Z * (xx - yy);
    f[15] = -0.5900435899266435f * X * (xx - 3.0f * yy);
    #pragma unroll
    for (int o = 0; o < 16; ++o) f[16 + o] = hh[o];

    float b1[64];
    #pragma unroll
    for (int j = 0; j < 64; ++j) {
        float s = 0.f;
        #pragma unroll
        for (int k = 0; k < 32; ++k) s = fmaf(f[k], rgb_w0[j * 32 + k], s);
        b1[j] = fmaxf(s, 0.f);
    }
    float b2[64];
    #pragma unroll
    for (int j = 0; j < 64; ++j) {
        float s = 0.f;
        #pragma unroll
        for (int k = 0; k < 64; ++k) s = fmaf(b1[k], rgb_w1[j * 64 + k], s);
        b2[j] = fmaxf(s, 0.f);
    }
    #pragma unroll
    for (int o = 0; o < 3; ++o) {
        float s = 0.f;
        #pragma unroll
        for (int k = 0; k < 64; ++k) s = fmaf(b2[k], rgb_wout[o * 64 + k], s);
        out[n + 3 * i + o] = 1.0f / (1.0f + expf(-s));
    }
}

extern "C" void kernel_launch(void* const* d_in, const int* in_sizes, int n_in,
                              void* d_out, int out_size, void* d_ws, size_t ws_size,
                              hipStream_t stream) {
    const float* x        = (const float*)d_in[0];
    const float* d        = (const float*)d_in[1];
    const float* table    = (const float*)d_in[2];
    const float* xyz_w0   = (const float*)d_in[3];
    const float* xyz_wout = (const float*)d_in[4];
    const float* rgb_w0   = (const float*)d_in[5];
    const float* rgb_w1   = (const float*)d_in[6];
    const float* rgb_wout = (const float*)d_in[7];
    float* out = (float*)d_out;

    int n = in_sizes[0] / 3;

    // resolution table in float64 exactly like numpy (level 14 = 1482.0045;
    // f32 recompute could floor to 1481 and corrupt every level-14 hash)
    ResTable rt;
    double b = std::exp((std::log(2048.0) - std::log(16.0)) / 15.0);
    for (int l = 0; l < NLEVELS; ++l)
        rt.r[l] = (float)std::floor(16.0 * std::pow(b, (double)l));

    int n_pairs = NLEVELS * TSIZE;
    char* ws = (char*)d_ws;
    int blocks = (n + 255) / 256;
    int cb = (n_pairs + 255) / 256;

    if (ws_size >= (size_t)WS_TOTAL) {
        uint32_t* tbl16  = (uint32_t*)(ws + WS_TBL);
        uint2*    embT   = (uint2*)   (ws + WS_EMB);
        float*    woutT  = (float*)   (ws + WS_WOUTT);
        float*    w1T    = (float*)   (ws + WS_W1T);
        float*    rwoutT = (float*)   (ws + WS_RWOUTT);
        hipLaunchKernelGGL(conv_table, dim3(cb), dim3(256), 0, stream,
                           table, tbl16, n_pairs);
        hipLaunchKernelGGL(prep_weights, dim3(21), dim3(256), 0, stream,
                           xyz_wout, rgb_w1, rgb_wout, woutT, w1T, rwoutT);
        hipLaunchKernelGGL(ngp_encode, dim3(blocks * 8), dim3(256), 0, stream,
                           x, tbl16, embT, rt, n);
        hipLaunchKernelGGL(ngp_mlp, dim3(blocks), dim3(256), 0, stream,
                           embT, d, xyz_w0, woutT, rgb_w0, w1T, rwoutT, out, n);
    } else if (ws_size >= (size_t)n_pairs * 4u) {
        uint32_t* tbl16 = (uint32_t*)d_ws;
        hipLaunchKernelGGL(conv_table, dim3(cb), dim3(256), 0, stream,
                           table, tbl16, n_pairs);
        hipLaunchKernelGGL(ngp_fused_bf16, dim3(blocks), dim3(256), 0, stream,
                           x, d, tbl16, xyz_w0, xyz_wout, rgb_w0, rgb_w1,
                           rgb_wout, out, rt, n);
    }
}

// Round 5
// 206.371 us; speedup vs baseline: 1.3221x; 1.3221x over previous
//
#include <hip/hip_runtime.h>
#include <cmath>
#include <cstdint>

#define NLEVELS 16
#define LOG2T 19
#define TSIZE (1u << LOG2T)
#define P1 2654435761u
#define P2 805459861u

struct ResTable { float r[NLEVELS]; };

// ---- ws layout (bytes) ----
#define WS_TBL    0u                      // 16*TSIZE*4  = 33,554,432  packed bf16 table
#define WS_EMB    33554432u               // 8*N*8       = 16,777,216  packed bf16 emb
#define WS_WOUTT  50331648u               // 64*16*4     = 4,096       xyz_wout^T
#define WS_W1T    50335744u               // 64*64*4     = 16,384      rgb_w1^T
#define WS_RWOUTT 50352128u               // 64*3*4      = 768         rgb_wout^T
#define WS_TOTAL  50352896u

__device__ inline uint16_t f32_to_bf16_rne(float f) {
    uint32_t u = __float_as_uint(f);
    uint32_t rounding = 0x7fffu + ((u >> 16) & 1u);
    return (uint16_t)((u + rounding) >> 16);
}

// ---------------------------------------------------------------------------
// Prep 0: f32 table (L,T,2) -> packed bf16 (L,T) uint32. 4 pairs per thread.
// ---------------------------------------------------------------------------
__global__ __launch_bounds__(256) void conv_table(
    const float* __restrict__ t, uint32_t* __restrict__ o, int n_quads)
{
    int i = blockIdx.x * blockDim.x + threadIdx.x;   // one uint4 (4 pairs) out
    if (i >= n_quads) return;
    float4 a = *reinterpret_cast<const float4*>(t + 8 * (size_t)i);
    float4 b = *reinterpret_cast<const float4*>(t + 8 * (size_t)i + 4);
    uint4 r;
    r.x = (uint32_t)f32_to_bf16_rne(a.x) | ((uint32_t)f32_to_bf16_rne(a.y) << 16);
    r.y = (uint32_t)f32_to_bf16_rne(a.z) | ((uint32_t)f32_to_bf16_rne(a.w) << 16);
    r.z = (uint32_t)f32_to_bf16_rne(b.x) | ((uint32_t)f32_to_bf16_rne(b.y) << 16);
    r.w = (uint32_t)f32_to_bf16_rne(b.z) | ((uint32_t)f32_to_bf16_rne(b.w) << 16);
    *reinterpret_cast<uint4*>(o + 4 * (size_t)i) = r;
}

// ---------------------------------------------------------------------------
// Prep 1: transpose column-accessed weight matrices into ws (f32).
// ---------------------------------------------------------------------------
__global__ __launch_bounds__(256) void prep_weights(
    const float* __restrict__ xyz_wout, const float* __restrict__ rgb_w1,
    const float* __restrict__ rgb_wout, float* __restrict__ woutT,
    float* __restrict__ w1T, float* __restrict__ rwoutT)
{
    int t = blockIdx.x * blockDim.x + threadIdx.x;
    if (t < 1024) {
        int j = t >> 4, o = t & 15;
        woutT[t] = xyz_wout[o * 64 + j];
    } else if (t < 5120) {
        int e = t - 1024; int j = e >> 6, jj = e & 63;
        w1T[e] = rgb_w1[jj * 64 + j];
    } else if (t < 5312) {
        int e = t - 5120; int j = e / 3, o = e % 3;
        rwoutT[e] = rgb_wout[o * 64 + j];
    }
}

// ---------------------------------------------------------------------------
// Kernel 1: hash encode, 2 levels (slot, slot+8) per thread, XCD-pinned.
// x-prime == 1  =>  for even xi0 the two x-corners of a (y,z) pair are the
// aligned uint2 {h, h^1}: one 8B load replaces two 4B loads (-25% L1/L2
// transactions in expectation). Odd xi0 falls back to two dword loads.
// ---------------------------------------------------------------------------
__global__ __launch_bounds__(256) void ngp_encode(
    const float* __restrict__ x, const uint32_t* __restrict__ tbl,
    uint2* __restrict__ embT, ResTable res, int n)
{
    int slot = blockIdx.x & 7;
    int i = (blockIdx.x >> 3) * 256 + threadIdx.x;
    if (i >= n) return;

    float xn0 = x[3 * i + 0] + 0.5f;
    float xn1 = x[3 * i + 1] + 0.5f;
    float xn2 = x[3 * i + 2] + 0.5f;

    uint32_t vx[16];        // corner values: [ll*8 + 2q + xoff]
    float    wyz[8];        // [ll*4 + q]
    float    wx0[2], wx1[2];

    #pragma unroll
    for (int ll = 0; ll < 2; ++ll) {
        int l = slot + ll * 8;
        float r  = res.r[l];
        float p0 = xn0 * r, p1 = xn1 * r, p2 = xn2 * r;
        float f0 = floorf(p0), f1 = floorf(p1), f2 = floorf(p2);
        float fr0 = p0 - f0, fr1 = p1 - f1, fr2 = p2 - f2;
        uint32_t xi0 = (uint32_t)f0, xi1 = (uint32_t)f1, xi2 = (uint32_t)f2;
        uint32_t hy0 = xi1 * P1, hy1 = (xi1 + 1u) * P1;
        uint32_t hz0 = xi2 * P2, hz1 = (xi2 + 1u) * P2;
        uint32_t base[4] = { hy0 ^ hz0, hy0 ^ hz1, hy1 ^ hz0, hy1 ^ hz1 };
        wx0[ll] = 1.f - fr0;  wx1[ll] = fr0;
        wyz[ll * 4 + 0] = (1.f - fr1) * (1.f - fr2);
        wyz[ll * 4 + 1] = (1.f - fr1) * fr2;
        wyz[ll * 4 + 2] = fr1 * (1.f - fr2);
        wyz[ll * 4 + 3] = fr1 * fr2;

        const uint32_t* tl  = tbl + (size_t)l * (size_t)TSIZE;
        const uint2*    tl2 = reinterpret_cast<const uint2*>(tl);

        if ((xi0 & 1u) == 0u) {
            // even: h1 = h0^1 -> one aligned uint2 per (y,z) pair
            #pragma unroll
            for (int q = 0; q < 4; ++q) {
                uint32_t h0 = (xi0 ^ base[q]) & (TSIZE - 1u);
                uint2 pv = tl2[h0 >> 1];
                uint32_t lo = (h0 & 1u) ? pv.y : pv.x;   // x0 corner
                uint32_t hi = (h0 & 1u) ? pv.x : pv.y;   // x1 corner
                vx[ll * 8 + 2 * q]     = lo;
                vx[ll * 8 + 2 * q + 1] = hi;
            }
        } else {
            #pragma unroll
            for (int q = 0; q < 4; ++q) {
                uint32_t h0 = (xi0        ^ base[q]) & (TSIZE - 1u);
                uint32_t h1 = ((xi0 + 1u) ^ base[q]) & (TSIZE - 1u);
                vx[ll * 8 + 2 * q]     = tl[h0];
                vx[ll * 8 + 2 * q + 1] = tl[h1];
            }
        }
    }

    uint2 o;
    #pragma unroll
    for (int ll = 0; ll < 2; ++ll) {
        float a0 = 0.f, a1 = 0.f;
        #pragma unroll
        for (int q = 0; q < 4; ++q) {
            uint32_t v0 = vx[ll * 8 + 2 * q];
            uint32_t v1 = vx[ll * 8 + 2 * q + 1];
            // per-corner weight = wyz * wx  (same products as reference)
            float w0 = wyz[ll * 4 + q] * wx0[ll];
            float w1 = wyz[ll * 4 + q] * wx1[ll];
            a0 = fmaf(w0, __uint_as_float(v0 << 16), a0);
            a0 = fmaf(w1, __uint_as_float(v1 << 16), a0);
            a1 = fmaf(w0, __uint_as_float(v0 & 0xffff0000u), a1);
            a1 = fmaf(w1, __uint_as_float(v1 & 0xffff0000u), a1);
        }
        uint32_t pk = (uint32_t)f32_to_bf16_rne(a0) |
                      ((uint32_t)f32_to_bf16_rne(a1) << 16);
        if (ll == 0) o.x = pk; else o.y = pk;
    }
    embT[(size_t)slot * n + i] = o;
}

// ---------------------------------------------------------------------------
// Kernel 2: SH + MLPs. Streaming accumulators + 4-way split dot products
// (break the 32-long dependent FMA chains; 4-cyc dep latency vs 2-cyc issue).
// ---------------------------------------------------------------------------
__global__ __launch_bounds__(256, 4) void ngp_mlp(
    const uint2* __restrict__ embT,     // (8, N) packed bf16
    const float* __restrict__ d,        // (N,3)
    const float* __restrict__ xyz_w0,   // (64,32) row-major
    const float* __restrict__ woutT,    // (64,16)
    const float* __restrict__ rgb_w0,   // (64,32) row-major
    const float* __restrict__ w1T,      // (64,64)
    const float* __restrict__ rwoutT,   // (64,3)
    float* __restrict__ out, int n)
{
    int i = blockIdx.x * blockDim.x + threadIdx.x;
    if (i >= n) return;

    float emb[32];
    #pragma unroll
    for (int s = 0; s < 8; ++s) {
        uint2 w = embT[(size_t)s * n + i];
        emb[2 * s + 0]       = __uint_as_float(w.x << 16);
        emb[2 * s + 1]       = __uint_as_float(w.x & 0xffff0000u);
        emb[2 * (s + 8) + 0] = __uint_as_float(w.y << 16);
        emb[2 * (s + 8) + 1] = __uint_as_float(w.y & 0xffff0000u);
    }

    // xyz MLP 32 -> 64(ReLU) -> 16, streaming
    float hh[16];
    #pragma unroll
    for (int o = 0; o < 16; ++o) hh[o] = 0.f;
    #pragma unroll
    for (int j = 0; j < 64; ++j) {
        const float* wr = xyz_w0 + j * 32;
        float s0 = 0.f, s1 = 0.f, s2 = 0.f, s3 = 0.f;
        #pragma unroll
        for (int k = 0; k < 32; k += 4) {
            s0 = fmaf(emb[k + 0], wr[k + 0], s0);
            s1 = fmaf(emb[k + 1], wr[k + 1], s1);
            s2 = fmaf(emb[k + 2], wr[k + 2], s2);
            s3 = fmaf(emb[k + 3], wr[k + 3], s3);
        }
        float s = fmaxf((s0 + s1) + (s2 + s3), 0.f);
        #pragma unroll
        for (int o = 0; o < 16; ++o) hh[o] = fmaf(s, woutT[j * 16 + o], hh[o]);
    }
    out[i] = expf(hh[0]);   // sigma

    // SH degree-4
    float dx = d[3 * i + 0], dy = d[3 * i + 1], dz = d[3 * i + 2];
    float inv = rsqrtf(dx * dx + dy * dy + dz * dz);
    float X = dx * inv, Y = dy * inv, Z = dz * inv;
    float xx = X * X, yy = Y * Y, zz = Z * Z;
    float xy = X * Y, yz = Y * Z, xz = X * Z;

    float f[32];
    f[0]  = 0.28209479177387814f;
    f[1]  = -0.4886025119029199f * Y;
    f[2]  =  0.4886025119029199f * Z;
    f[3]  = -0.4886025119029199f * X;
    f[4]  =  1.0925484305920792f * xy;
    f[5]  = -1.0925484305920792f * yz;
    f[6]  =  0.31539156525252005f * (3.0f * zz - 1.0f);
    f[7]  = -1.0925484305920792f * xz;
    f[8]  =  0.5462742152960396f * (xx - yy);
    f[9]  = -0.5900435899266435f * Y * (3.0f * xx - yy);
    f[10] =  2.890611442640554f * xy * Z;
    f[11] = -0.4570457994644658f * Y * (4.0f * zz - xx - yy);
    f[12] =  0.3731763325901154f * Z * (2.0f * zz - 3.0f * xx - 3.0f * yy);
    f[13] = -0.4570457994644658f * X * (4.0f * zz - xx - yy);
    f[14] =  1.445305721320277f * Z * (xx - yy);
    f[15] = -0.5900435899266435f * X * (xx - 3.0f * yy);
    #pragma unroll
    for (int o = 0; o < 16; ++o) f[16 + o] = hh[o];

    // rgb MLP 32 -> 64(ReLU) -> 64(ReLU) -> 3(sigmoid), streaming into b2
    float b2[64];
    #pragma unroll
    for (int j = 0; j < 64; ++j) b2[j] = 0.f;
    #pragma unroll
    for (int j = 0; j < 64; ++j) {
        const float* wr = rgb_w0 + j * 32;
        float s0 = 0.f, s1 = 0.f, s2 = 0.f, s3 = 0.f;
        #pragma unroll
        for (int k = 0; k < 32; k += 4) {
            s0 = fmaf(f[k + 0], wr[k + 0], s0);
            s1 = fmaf(f[k + 1], wr[k + 1], s1);
            s2 = fmaf(f[k + 2], wr[k + 2], s2);
            s3 = fmaf(f[k + 3], wr[k + 3], s3);
        }
        float s = fmaxf((s0 + s1) + (s2 + s3), 0.f);
        #pragma unroll
        for (int jj = 0; jj < 64; ++jj) b2[jj] = fmaf(s, w1T[j * 64 + jj], b2[jj]);
    }
    float o3[3] = {0.f, 0.f, 0.f};
    #pragma unroll
    for (int j = 0; j < 64; ++j) {
        float s = fmaxf(b2[j], 0.f);
        #pragma unroll
        for (int o = 0; o < 3; ++o) o3[o] = fmaf(s, rwoutT[j * 3 + o], o3[o]);
    }
    #pragma unroll
    for (int o = 0; o < 3; ++o)
        out[n + 3 * i + o] = 1.0f / (1.0f + expf(-o3[o]));
}

// ---------------------------------------------------------------------------
// Fallback (ws >= 33.5MB only): round-3 fused bf16 kernel.
// ---------------------------------------------------------------------------
__global__ __launch_bounds__(256) void ngp_fused_bf16(
    const float* __restrict__ x, const float* __restrict__ d,
    const uint32_t* __restrict__ tbl,
    const float* __restrict__ xyz_w0, const float* __restrict__ xyz_wout,
    const float* __restrict__ rgb_w0, const float* __restrict__ rgb_w1,
    const float* __restrict__ rgb_wout, float* __restrict__ out,
    ResTable res, int n)
{
    int i = blockIdx.x * blockDim.x + threadIdx.x;
    if (i >= n) return;

    float xn0 = x[3 * i + 0] + 0.5f;
    float xn1 = x[3 * i + 1] + 0.5f;
    float xn2 = x[3 * i + 2] + 0.5f;

    float emb[NLEVELS * 2];
    #pragma unroll
    for (int b = 0; b < 4; ++b) {
        uint32_t idx[32]; float wg[32];
        #pragma unroll
        for (int ll = 0; ll < 4; ++ll) {
            int l = b * 4 + ll;
            float r  = res.r[l];
            float p0 = xn0 * r, p1 = xn1 * r, p2 = xn2 * r;
            float f0 = floorf(p0), f1 = floorf(p1), f2 = floorf(p2);
            float fr0 = p0 - f0, fr1 = p1 - f1, fr2 = p2 - f2;
            uint32_t xi0 = (uint32_t)f0, xi1 = (uint32_t)f1, xi2 = (uint32_t)f2;
            uint32_t hx0 = xi0,          hx1 = xi0 + 1u;
            uint32_t hy0 = xi1 * P1,     hy1 = (xi1 + 1u) * P1;
            uint32_t hz0 = xi2 * P2,     hz1 = (xi2 + 1u) * P2;
            #pragma unroll
            for (int c = 0; c < 8; ++c) {
                uint32_t hx = (c & 4) ? hx1 : hx0;
                uint32_t hy = (c & 2) ? hy1 : hy0;
                uint32_t hz = (c & 1) ? hz1 : hz0;
                idx[ll * 8 + c] = (hx ^ hy ^ hz) & (TSIZE - 1u);
                float wx = (c & 4) ? fr0 : 1.f - fr0;
                float wy = (c & 2) ? fr1 : 1.f - fr1;
                float wz = (c & 1) ? fr2 : 1.f - fr2;
                wg[ll * 8 + c] = wx * wy * wz;
            }
        }
        uint32_t val[32];
        #pragma unroll
        for (int ll = 0; ll < 4; ++ll) {
            const uint32_t* tl = tbl + (size_t)(b * 4 + ll) * (size_t)TSIZE;
            #pragma unroll
            for (int c = 0; c < 8; ++c) val[ll * 8 + c] = tl[idx[ll * 8 + c]];
        }
        #pragma unroll
        for (int ll = 0; ll < 4; ++ll) {
            float a0 = 0.f, a1 = 0.f;
            #pragma unroll
            for (int c = 0; c < 8; ++c) {
                uint32_t pv = val[ll * 8 + c];
                float w = wg[ll * 8 + c];
                a0 = fmaf(w, __uint_as_float(pv << 16), a0);
                a1 = fmaf(w, __uint_as_float(pv & 0xffff0000u), a1);
            }
            emb[2 * (b * 4 + ll)]     = a0;
            emb[2 * (b * 4 + ll) + 1] = a1;
        }
    }

    float h1[64];
    #pragma unroll
    for (int j = 0; j < 64; ++j) {
        float s = 0.f;
        #pragma unroll
        for (int k = 0; k < 32; ++k) s = fmaf(emb[k], xyz_w0[j * 32 + k], s);
        h1[j] = fmaxf(s, 0.f);
    }
    float hh[16];
    #pragma unroll
    for (int o = 0; o < 16; ++o) {
        float s = 0.f;
        #pragma unroll
        for (int k = 0; k < 64; ++k) s = fmaf(h1[k], xyz_wout[o * 64 + k], s);
        hh[o] = s;
    }
    out[i] = expf(hh[0]);

    float dx = d[3 * i + 0], dy = d[3 * i + 1], dz = d[3 * i + 2];
    float inv = rsqrtf(dx * dx + dy * dy + dz * dz);
    float X = dx * inv, Y = dy * inv, Z = dz * inv;
    float xx = X * X, yy = Y * Y, zz = Z * Z;
    float xy = X * Y, yz = Y * Z, xz = X * Z;

    float f[32];
    f[0]  = 0.28209479177387814f;
    f[1]  = -0.4886025119029199f * Y;
    f[2]  =  0.4886025119029199f * Z;
    f[3]  = -0.4886025119029199f * X;
    f[4]  =  1.0925484305920792f * xy;
    f[5]  = -1.0925484305920792f * yz;
    f[6]  =  0.31539156525252005f * (3.0f * zz - 1.0f);
    f[7]  = -1.0925484305920792f * xz;
    f[8]  =  0.5462742152960396f * (xx - yy);
    f[9]  = -0.5900435899266435f * Y * (3.0f * xx - yy);
    f[10] =  2.890611442640554f * xy * Z;
    f[11] = -0.4570457994644658f * Y * (4.0f * zz - xx - yy);
    f[12] =  0.3731763325901154f * Z * (2.0f * zz - 3.0f * xx - 3.0f * yy);
    f[13] = -0.4570457994644658f * X * (4.0f * zz - xx - yy);
    f[14] =  1.445305721320277f * Z * (xx - yy);
    f[15] = -0.5900435899266435f * X * (xx - 3.0f * yy);
    #pragma unroll
    for (int o = 0; o < 16; ++o) f[16 + o] = hh[o];

    float b1[64];
    #pragma unroll
    for (int j = 0; j < 64; ++j) {
        float s = 0.f;
        #pragma unroll
        for (int k = 0; k < 32; ++k) s = fmaf(f[k], rgb_w0[j * 32 + k], s);
        b1[j] = fmaxf(s, 0.f);
    }
    float b2[64];
    #pragma unroll
    for (int j = 0; j < 64; ++j) {
        float s = 0.f;
        #pragma unroll
        for (int k = 0; k < 64; ++k) s = fmaf(b1[k], rgb_w1[j * 64 + k], s);
        b2[j] = fmaxf(s, 0.f);
    }
    #pragma unroll
    for (int o = 0; o < 3; ++o) {
        float s = 0.f;
        #pragma unroll
        for (int k = 0; k < 64; ++k) s = fmaf(b2[k], rgb_wout[o * 64 + k], s);
        out[n + 3 * i + o] = 1.0f / (1.0f + expf(-s));
    }
}

extern "C" void kernel_launch(void* const* d_in, const int* in_sizes, int n_in,
                              void* d_out, int out_size, void* d_ws, size_t ws_size,
                              hipStream_t stream) {
    const float* x        = (const float*)d_in[0];
    const float* d        = (const float*)d_in[1];
    const float* table    = (const float*)d_in[2];
    const float* xyz_w0   = (const float*)d_in[3];
    const float* xyz_wout = (const float*)d_in[4];
    const float* rgb_w0   = (const float*)d_in[5];
    const float* rgb_w1   = (const float*)d_in[6];
    const float* rgb_wout = (const float*)d_in[7];
    float* out = (float*)d_out;

    int n = in_sizes[0] / 3;

    // resolution table in float64 exactly like numpy (level 14 = 1482.0045;
    // f32 recompute could floor to 1481 and corrupt every level-14 hash)
    ResTable rt;
    double b = std::exp((std::log(2048.0) - std::log(16.0)) / 15.0);
    for (int l = 0; l < NLEVELS; ++l)
        rt.r[l] = (float)std::floor(16.0 * std::pow(b, (double)l));

    int n_pairs = NLEVELS * TSIZE;
    int n_quads = n_pairs / 4;
    char* ws = (char*)d_ws;
    int blocks = (n + 255) / 256;

    if (ws_size >= (size_t)WS_TOTAL) {
        uint32_t* tbl16  = (uint32_t*)(ws + WS_TBL);
        uint2*    embT   = (uint2*)   (ws + WS_EMB);
        float*    woutT  = (float*)   (ws + WS_WOUTT);
        float*    w1T    = (float*)   (ws + WS_W1T);
        float*    rwoutT = (float*)   (ws + WS_RWOUTT);
        hipLaunchKernelGGL(conv_table, dim3((n_quads + 255) / 256), dim3(256),
                           0, stream, table, tbl16, n_quads);
        hipLaunchKernelGGL(prep_weights, dim3(21), dim3(256), 0, stream,
                           xyz_wout, rgb_w1, rgb_wout, woutT, w1T, rwoutT);
        hipLaunchKernelGGL(ngp_encode, dim3(blocks * 8), dim3(256), 0, stream,
                           x, tbl16, embT, rt, n);
        hipLaunchKernelGGL(ngp_mlp, dim3(blocks), dim3(256), 0, stream,
                           embT, d, xyz_w0, woutT, rgb_w0, w1T, rwoutT, out, n);
    } else if (ws_size >= (size_t)n_pairs * 4u) {
        uint32_t* tbl16 = (uint32_t*)d_ws;
        hipLaunchKernelGGL(conv_table, dim3((n_quads + 255) / 256), dim3(256),
                           0, stream, table, tbl16, n_quads);
        hipLaunchKernelGGL(ngp_fused_bf16, dim3(blocks), dim3(256), 0, stream,
                           x, d, tbl16, xyz_w0, xyz_wout, rgb_w0, rgb_w1,
                           rgb_wout, out, rt, n);
    }
}

// Round 6
// 122.110 us; speedup vs baseline: 2.2344x; 1.6900x over previous
//
#include <hip/hip_runtime.h>
#include <cmath>
#include <cstdint>

#define NLEVELS 16
#define LOG2T 19
#define TSIZE (1u << LOG2T)
#define P1 2654435761u
#define P2 805459861u

struct ResTable { float r[NLEVELS]; };

typedef __attribute__((ext_vector_type(8))) short bf16x8;
typedef __attribute__((ext_vector_type(4))) float f32x4;

// ---- ws layout (bytes) ----
#define WS_TBL    0u                      // 16*TSIZE*4  = 33,554,432  packed bf16 table
#define WS_EMB    33554432u               // 8*N*8       = 16,777,216  packed bf16 emb
#define WS_WFRAG  50331648u               // 20 frags * 64 lanes * 16B = 20,480
#define WS_TOTAL  50352128u

__device__ __host__ inline uint16_t f32_to_bf16_rne_h(float f) {
    union { float f; uint32_t u; } c; c.f = f;
    uint32_t rounding = 0x7fffu + ((c.u >> 16) & 1u);
    return (uint16_t)((c.u + rounding) >> 16);
}
__device__ inline uint16_t f32_to_bf16_rne(float f) {
    uint32_t u = __float_as_uint(f);
    uint32_t rounding = 0x7fffu + ((u >> 16) & 1u);
    return (uint16_t)((u + rounding) >> 16);
}

// ---------------------------------------------------------------------------
// Prep 0: f32 table (L,T,2) -> packed bf16 (L,T) uint32. 4 pairs per thread.
// ---------------------------------------------------------------------------
__global__ __launch_bounds__(256) void conv_table(
    const float* __restrict__ t, uint32_t* __restrict__ o, int n_quads)
{
    int i = blockIdx.x * blockDim.x + threadIdx.x;
    if (i >= n_quads) return;
    float4 a = *reinterpret_cast<const float4*>(t + 8 * (size_t)i);
    float4 b = *reinterpret_cast<const float4*>(t + 8 * (size_t)i + 4);
    uint4 r;
    r.x = (uint32_t)f32_to_bf16_rne(a.x) | ((uint32_t)f32_to_bf16_rne(a.y) << 16);
    r.y = (uint32_t)f32_to_bf16_rne(a.z) | ((uint32_t)f32_to_bf16_rne(a.w) << 16);
    r.z = (uint32_t)f32_to_bf16_rne(b.x) | ((uint32_t)f32_to_bf16_rne(b.y) << 16);
    r.w = (uint32_t)f32_to_bf16_rne(b.z) | ((uint32_t)f32_to_bf16_rne(b.w) << 16);
    *reinterpret_cast<uint4*>(o + 4 * (size_t)i) = r;
}

// ---------------------------------------------------------------------------
// Prep 1: pack all MLP weights into MFMA B-fragments (bf16).
// Frag f, lane l, dword dw: elem e=2dw+h holds W[out = 16*tile + (l&15)]
// [feat = 32*khalf + 8*(l>>4) + e].  A-side uses the identical feature map,
// so the hardware's internal k ordering cancels (A/B layouts symmetric).
// frags: 0-3 xyz_w0(K32,t0-3) | 4-5 xyz_wout(K64,h0-1) | 6-9 rgb_w0(K32)
//        10-17 rgb_w1(K64, t*2+h) | 18-19 rgb_wout(K64, outs padded 3->16)
// ---------------------------------------------------------------------------
__global__ __launch_bounds__(256) void prep_wfrag(
    const float* __restrict__ xyz_w0, const float* __restrict__ xyz_wout,
    const float* __restrict__ rgb_w0, const float* __restrict__ rgb_w1,
    const float* __restrict__ rgb_wout, uint32_t* __restrict__ wf)
{
    int t = blockIdx.x * blockDim.x + threadIdx.x;
    if (t >= 20 * 64) return;
    int frag = t >> 6, lane = t & 63;
    int outc = lane & 15, g = lane >> 4;

    const float* W; int K, nout, tile, h;
    if (frag < 4)       { W = xyz_w0;   K = 32; nout = 64; tile = frag;          h = 0; }
    else if (frag < 6)  { W = xyz_wout; K = 64; nout = 16; tile = 0;             h = frag - 4; }
    else if (frag < 10) { W = rgb_w0;   K = 32; nout = 64; tile = frag - 6;      h = 0; }
    else if (frag < 18) { W = rgb_w1;   K = 64; nout = 64; tile = (frag - 10) >> 1; h = (frag - 10) & 1; }
    else                { W = rgb_wout; K = 64; nout = 3;  tile = 0;             h = frag - 18; }

    int out = tile * 16 + outc;
    uint4 r;
    uint32_t dws[4];
    #pragma unroll
    for (int dw = 0; dw < 4; ++dw) {
        int f0 = 32 * h + 8 * g + 2 * dw;
        uint32_t lo = (out < nout) ? f32_to_bf16_rne(W[out * K + f0])     : 0u;
        uint32_t hi = (out < nout) ? f32_to_bf16_rne(W[out * K + f0 + 1]) : 0u;
        dws[dw] = lo | (hi << 16);
    }
    r.x = dws[0]; r.y = dws[1]; r.z = dws[2]; r.w = dws[3];
    *reinterpret_cast<uint4*>(wf + 4 * (size_t)(frag * 64 + lane)) = r;
}

// ---------------------------------------------------------------------------
// Kernel 1: hash encode, 2 levels (slot, slot+8) per thread, XCD-pinned,
// paired-corner 8B loads when xi0 even (x-prime == 1).  Unchanged from r5.
// ---------------------------------------------------------------------------
__global__ __launch_bounds__(256) void ngp_encode(
    const float* __restrict__ x, const uint32_t* __restrict__ tbl,
    uint2* __restrict__ embT, ResTable res, int n)
{
    int slot = blockIdx.x & 7;
    int i = (blockIdx.x >> 3) * 256 + threadIdx.x;
    if (i >= n) return;

    float xn0 = x[3 * i + 0] + 0.5f;
    float xn1 = x[3 * i + 1] + 0.5f;
    float xn2 = x[3 * i + 2] + 0.5f;

    uint32_t vx[16];
    float    wyz[8];
    float    wx0[2], wx1[2];

    #pragma unroll
    for (int ll = 0; ll < 2; ++ll) {
        int l = slot + ll * 8;
        float r  = res.r[l];
        float p0 = xn0 * r, p1 = xn1 * r, p2 = xn2 * r;
        float f0 = floorf(p0), f1 = floorf(p1), f2 = floorf(p2);
        float fr0 = p0 - f0, fr1 = p1 - f1, fr2 = p2 - f2;
        uint32_t xi0 = (uint32_t)f0, xi1 = (uint32_t)f1, xi2 = (uint32_t)f2;
        uint32_t hy0 = xi1 * P1, hy1 = (xi1 + 1u) * P1;
        uint32_t hz0 = xi2 * P2, hz1 = (xi2 + 1u) * P2;
        uint32_t base[4] = { hy0 ^ hz0, hy0 ^ hz1, hy1 ^ hz0, hy1 ^ hz1 };
        wx0[ll] = 1.f - fr0;  wx1[ll] = fr0;
        wyz[ll * 4 + 0] = (1.f - fr1) * (1.f - fr2);
        wyz[ll * 4 + 1] = (1.f - fr1) * fr2;
        wyz[ll * 4 + 2] = fr1 * (1.f - fr2);
        wyz[ll * 4 + 3] = fr1 * fr2;

        const uint32_t* tl  = tbl + (size_t)l * (size_t)TSIZE;
        const uint2*    tl2 = reinterpret_cast<const uint2*>(tl);

        if ((xi0 & 1u) == 0u) {
            #pragma unroll
            for (int q = 0; q < 4; ++q) {
                uint32_t h0 = (xi0 ^ base[q]) & (TSIZE - 1u);
                uint2 pv = tl2[h0 >> 1];
                uint32_t lo = (h0 & 1u) ? pv.y : pv.x;
                uint32_t hi = (h0 & 1u) ? pv.x : pv.y;
                vx[ll * 8 + 2 * q]     = lo;
                vx[ll * 8 + 2 * q + 1] = hi;
            }
        } else {
            #pragma unroll
            for (int q = 0; q < 4; ++q) {
                uint32_t h0 = (xi0        ^ base[q]) & (TSIZE - 1u);
                uint32_t h1 = ((xi0 + 1u) ^ base[q]) & (TSIZE - 1u);
                vx[ll * 8 + 2 * q]     = tl[h0];
                vx[ll * 8 + 2 * q + 1] = tl[h1];
            }
        }
    }

    uint2 o;
    #pragma unroll
    for (int ll = 0; ll < 2; ++ll) {
        float a0 = 0.f, a1 = 0.f;
        #pragma unroll
        for (int q = 0; q < 4; ++q) {
            uint32_t v0 = vx[ll * 8 + 2 * q];
            uint32_t v1 = vx[ll * 8 + 2 * q + 1];
            float w0 = wyz[ll * 4 + q] * wx0[ll];
            float w1 = wyz[ll * 4 + q] * wx1[ll];
            a0 = fmaf(w0, __uint_as_float(v0 << 16), a0);
            a0 = fmaf(w1, __uint_as_float(v1 << 16), a0);
            a1 = fmaf(w0, __uint_as_float(v0 & 0xffff0000u), a1);
            a1 = fmaf(w1, __uint_as_float(v1 & 0xffff0000u), a1);
        }
        uint32_t pk = (uint32_t)f32_to_bf16_rne(a0) |
                      ((uint32_t)f32_to_bf16_rne(a1) << 16);
        if (ll == 0) o.x = pk; else o.y = pk;
    }
    embT[(size_t)slot * n + i] = o;
}

// ---------------------------------------------------------------------------
// Kernel 2: SH + MLPs via MFMA. One wave = 16 points per round, 4 rounds.
// Activations stage through per-wave LDS tile [16 pts][72 feats] (144B rows,
// b128-aligned). Weights live in block-shared LDS as prepacked B-frags.
// C/D layout (m89-verified): col = lane&15, row = (lane>>4)*4 + reg.
// ---------------------------------------------------------------------------
#define WF(idx) (*reinterpret_cast<const bf16x8*>(&wlds[((idx) * 64 + lane) * 4]))

#define STORE_RELU_TILE(cc, t)                                                  \
    a16[(g * 4 + 0) * 72 + (t) * 16 + outc] = f32_to_bf16_rne(fmaxf((cc)[0], 0.f)); \
    a16[(g * 4 + 1) * 72 + (t) * 16 + outc] = f32_to_bf16_rne(fmaxf((cc)[1], 0.f)); \
    a16[(g * 4 + 2) * 72 + (t) * 16 + outc] = f32_to_bf16_rne(fmaxf((cc)[2], 0.f)); \
    a16[(g * 4 + 3) * 72 + (t) * 16 + outc] = f32_to_bf16_rne(fmaxf((cc)[3], 0.f));

__global__ __launch_bounds__(256, 4) void ngp_mlp_mfma(
    const uint2* __restrict__ embT,     // (8, N) packed bf16
    const float* __restrict__ d,        // (N,3)
    const uint32_t* __restrict__ wfrag, // 20*64*4 dwords
    float* __restrict__ out, int n)
{
    __shared__ uint32_t wlds[20 * 64 * 4];
    __shared__ __attribute__((aligned(16))) uint16_t act[4][16 * 72];

    int tid = threadIdx.x;
    {
        const uint4* src = reinterpret_cast<const uint4*>(wfrag);
        uint4* dst = reinterpret_cast<uint4*>(wlds);
        #pragma unroll
        for (int k = 0; k < 5; ++k) dst[tid + 256 * k] = src[tid + 256 * k];
    }
    __syncthreads();

    int w = tid >> 6, lane = tid & 63;
    int outc = lane & 15, g = lane >> 4;
    uint16_t* a16 = act[w];
    uint32_t* a32 = reinterpret_cast<uint32_t*>(act[w]);

    const int ROUNDS = 4;
    int wave_global = blockIdx.x * 4 + w;

    for (int r = 0; r < ROUNDS; ++r) {
        int pt0 = (wave_global * ROUNDS + r) * 16;
        if (pt0 >= n) break;

        // issue global loads early
        int s = lane >> 3, pp = 2 * (lane & 7);
        uint4 ev = *reinterpret_cast<const uint4*>(embT + (size_t)s * n + pt0 + pp);
        int ptd = pt0 + outc;
        float dx = d[3 * ptd + 0], dy = d[3 * ptd + 1], dz = d[3 * ptd + 2];

        // stage emb -> act[pt][feat] (identity feature order)
        a32[pp * 36 + s]           = ev.x;
        a32[pp * 36 + 8 + s]       = ev.y;
        a32[(pp + 1) * 36 + s]     = ev.z;
        a32[(pp + 1) * 36 + 8 + s] = ev.w;

        // ---- xyz layer 1: 32 -> 64, ReLU
        bf16x8 a0 = *reinterpret_cast<const bf16x8*>(&a16[outc * 72 + g * 8]);
        f32x4 c0 = {0.f,0.f,0.f,0.f}, c1 = {0.f,0.f,0.f,0.f};
        f32x4 c2 = {0.f,0.f,0.f,0.f}, c3 = {0.f,0.f,0.f,0.f};
        c0 = __builtin_amdgcn_mfma_f32_16x16x32_bf16(a0, WF(0), c0, 0, 0, 0);
        c1 = __builtin_amdgcn_mfma_f32_16x16x32_bf16(a0, WF(1), c1, 0, 0, 0);
        c2 = __builtin_amdgcn_mfma_f32_16x16x32_bf16(a0, WF(2), c2, 0, 0, 0);
        c3 = __builtin_amdgcn_mfma_f32_16x16x32_bf16(a0, WF(3), c3, 0, 0, 0);
        STORE_RELU_TILE(c0, 0) STORE_RELU_TILE(c1, 1)
        STORE_RELU_TILE(c2, 2) STORE_RELU_TILE(c3, 3)

        // ---- xyz layer 2: 64 -> 16 (linear)
        bf16x8 a1a = *reinterpret_cast<const bf16x8*>(&a16[outc * 72 + g * 8]);
        bf16x8 a1b = *reinterpret_cast<const bf16x8*>(&a16[outc * 72 + 32 + g * 8]);
        f32x4 ch = {0.f,0.f,0.f,0.f};
        ch = __builtin_amdgcn_mfma_f32_16x16x32_bf16(a1a, WF(4), ch, 0, 0, 0);
        ch = __builtin_amdgcn_mfma_f32_16x16x32_bf16(a1b, WF(5), ch, 0, 0, 0);

        // sigma = exp(hh[:,0]) : col 0 lanes hold 4 consecutive points
        if (outc == 0) {
            float4 sg;
            sg.x = expf(ch[0]); sg.y = expf(ch[1]);
            sg.z = expf(ch[2]); sg.w = expf(ch[3]);
            *reinterpret_cast<float4*>(out + pt0 + g * 4) = sg;
        }
        // stage hh (no ReLU) into feats 16..31
        a16[(g * 4 + 0) * 72 + 16 + outc] = f32_to_bf16_rne(ch[0]);
        a16[(g * 4 + 1) * 72 + 16 + outc] = f32_to_bf16_rne(ch[1]);
        a16[(g * 4 + 2) * 72 + 16 + outc] = f32_to_bf16_rne(ch[2]);
        a16[(g * 4 + 3) * 72 + 16 + outc] = f32_to_bf16_rne(ch[3]);

        // ---- SH degree-4 into feats 0..15 (lane: pt = outc, comps 4g..4g+3)
        {
            float inv = rsqrtf(dx * dx + dy * dy + dz * dz);
            float X = dx * inv, Y = dy * inv, Z = dz * inv;
            float xx = X * X, yy = Y * Y, zz = Z * Z;
            float xy = X * Y, yz = Y * Z, xz = X * Z;
            float t0  = 0.28209479177387814f;
            float t1  = -0.4886025119029199f * Y;
            float t2  =  0.4886025119029199f * Z;
            float t3  = -0.4886025119029199f * X;
            float t4  =  1.0925484305920792f * xy;
            float t5  = -1.0925484305920792f * yz;
            float t6  =  0.31539156525252005f * (3.0f * zz - 1.0f);
            float t7  = -1.0925484305920792f * xz;
            float t8  =  0.5462742152960396f * (xx - yy);
            float t9  = -0.5900435899266435f * Y * (3.0f * xx - yy);
            float t10 =  2.890611442640554f * xy * Z;
            float t11 = -0.4570457994644658f * Y * (4.0f * zz - xx - yy);
            float t12 =  0.3731763325901154f * Z * (2.0f * zz - 3.0f * xx - 3.0f * yy);
            float t13 = -0.4570457994644658f * X * (4.0f * zz - xx - yy);
            float t14 =  1.445305721320277f * Z * (xx - yy);
            float t15 = -0.5900435899266435f * X * (xx - 3.0f * yy);
            float v0 = (g == 0) ? t0 : (g == 1) ? t4 : (g == 2) ? t8  : t12;
            float v1 = (g == 0) ? t1 : (g == 1) ? t5 : (g == 2) ? t9  : t13;
            float v2 = (g == 0) ? t2 : (g == 1) ? t6 : (g == 2) ? t10 : t14;
            float v3 = (g == 0) ? t3 : (g == 1) ? t7 : (g == 2) ? t11 : t15;
            uint2 pk;
            pk.x = (uint32_t)f32_to_bf16_rne(v0) | ((uint32_t)f32_to_bf16_rne(v1) << 16);
            pk.y = (uint32_t)f32_to_bf16_rne(v2) | ((uint32_t)f32_to_bf16_rne(v3) << 16);
            *reinterpret_cast<uint2*>(&a32[outc * 36 + g * 2]) = pk;
        }

        // ---- rgb layer 1: 32 -> 64, ReLU
        bf16x8 af = *reinterpret_cast<const bf16x8*>(&a16[outc * 72 + g * 8]);
        c0 = f32x4{0.f,0.f,0.f,0.f}; c1 = f32x4{0.f,0.f,0.f,0.f};
        c2 = f32x4{0.f,0.f,0.f,0.f}; c3 = f32x4{0.f,0.f,0.f,0.f};
        c0 = __builtin_amdgcn_mfma_f32_16x16x32_bf16(af, WF(6), c0, 0, 0, 0);
        c1 = __builtin_amdgcn_mfma_f32_16x16x32_bf16(af, WF(7), c1, 0, 0, 0);
        c2 = __builtin_amdgcn_mfma_f32_16x16x32_bf16(af, WF(8), c2, 0, 0, 0);
        c3 = __builtin_amdgcn_mfma_f32_16x16x32_bf16(af, WF(9), c3, 0, 0, 0);
        STORE_RELU_TILE(c0, 0) STORE_RELU_TILE(c1, 1)
        STORE_RELU_TILE(c2, 2) STORE_RELU_TILE(c3, 3)

        // ---- rgb layer 2: 64 -> 64, ReLU
        bf16x8 a2a = *reinterpret_cast<const bf16x8*>(&a16[outc * 72 + g * 8]);
        bf16x8 a2b = *reinterpret_cast<const bf16x8*>(&a16[outc * 72 + 32 + g * 8]);
        c0 = f32x4{0.f,0.f,0.f,0.f}; c1 = f32x4{0.f,0.f,0.f,0.f};
        c2 = f32x4{0.f,0.f,0.f,0.f}; c3 = f32x4{0.f,0.f,0.f,0.f};
        c0 = __builtin_amdgcn_mfma_f32_16x16x32_bf16(a2a, WF(10), c0, 0, 0, 0);
        c1 = __builtin_amdgcn_mfma_f32_16x16x32_bf16(a2a, WF(12), c1, 0, 0, 0);
        c2 = __builtin_amdgcn_mfma_f32_16x16x32_bf16(a2a, WF(14), c2, 0, 0, 0);
        c3 = __builtin_amdgcn_mfma_f32_16x16x32_bf16(a2a, WF(16), c3, 0, 0, 0);
        c0 = __builtin_amdgcn_mfma_f32_16x16x32_bf16(a2b, WF(11), c0, 0, 0, 0);
        c1 = __builtin_amdgcn_mfma_f32_16x16x32_bf16(a2b, WF(13), c1, 0, 0, 0);
        c2 = __builtin_amdgcn_mfma_f32_16x16x32_bf16(a2b, WF(15), c2, 0, 0, 0);
        c3 = __builtin_amdgcn_mfma_f32_16x16x32_bf16(a2b, WF(17), c3, 0, 0, 0);
        STORE_RELU_TILE(c0, 0) STORE_RELU_TILE(c1, 1)
        STORE_RELU_TILE(c2, 2) STORE_RELU_TILE(c3, 3)

        // ---- rgb out: 64 -> 3 (padded to 16), sigmoid
        bf16x8 a3a = *reinterpret_cast<const bf16x8*>(&a16[outc * 72 + g * 8]);
        bf16x8 a3b = *reinterpret_cast<const bf16x8*>(&a16[outc * 72 + 32 + g * 8]);
        f32x4 co = {0.f,0.f,0.f,0.f};
        co = __builtin_amdgcn_mfma_f32_16x16x32_bf16(a3a, WF(18), co, 0, 0, 0);
        co = __builtin_amdgcn_mfma_f32_16x16x32_bf16(a3b, WF(19), co, 0, 0, 0);
        if (outc < 3) {
            #pragma unroll
            for (int rr = 0; rr < 4; ++rr) {
                float v = 1.0f / (1.0f + expf(-co[rr]));
                out[n + (size_t)(pt0 + g * 4 + rr) * 3 + outc] = v;
            }
        }
    }
}

// ---------------------------------------------------------------------------
// Fallback (ws >= 33.5MB only): round-3 fused bf16 kernel.
// ---------------------------------------------------------------------------
__global__ __launch_bounds__(256) void ngp_fused_bf16(
    const float* __restrict__ x, const float* __restrict__ d,
    const uint32_t* __restrict__ tbl,
    const float* __restrict__ xyz_w0, const float* __restrict__ xyz_wout,
    const float* __restrict__ rgb_w0, const float* __restrict__ rgb_w1,
    const float* __restrict__ rgb_wout, float* __restrict__ out,
    ResTable res, int n)
{
    int i = blockIdx.x * blockDim.x + threadIdx.x;
    if (i >= n) return;

    float xn0 = x[3 * i + 0] + 0.5f;
    float xn1 = x[3 * i + 1] + 0.5f;
    float xn2 = x[3 * i + 2] + 0.5f;

    float emb[NLEVELS * 2];
    #pragma unroll
    for (int b = 0; b < 4; ++b) {
        uint32_t idx[32]; float wg[32];
        #pragma unroll
        for (int ll = 0; ll < 4; ++ll) {
            int l = b * 4 + ll;
            float r  = res.r[l];
            float p0 = xn0 * r, p1 = xn1 * r, p2 = xn2 * r;
            float f0 = floorf(p0), f1 = floorf(p1), f2 = floorf(p2);
            float fr0 = p0 - f0, fr1 = p1 - f1, fr2 = p2 - f2;
            uint32_t xi0 = (uint32_t)f0, xi1 = (uint32_t)f1, xi2 = (uint32_t)f2;
            uint32_t hx0 = xi0,          hx1 = xi0 + 1u;
            uint32_t hy0 = xi1 * P1,     hy1 = (xi1 + 1u) * P1;
            uint32_t hz0 = xi2 * P2,     hz1 = (xi2 + 1u) * P2;
            #pragma unroll
            for (int c = 0; c < 8; ++c) {
                uint32_t hx = (c & 4) ? hx1 : hx0;
                uint32_t hy = (c & 2) ? hy1 : hy0;
                uint32_t hz = (c & 1) ? hz1 : hz0;
                idx[ll * 8 + c] = (hx ^ hy ^ hz) & (TSIZE - 1u);
                float wx = (c & 4) ? fr0 : 1.f - fr0;
                float wy = (c & 2) ? fr1 : 1.f - fr1;
                float wz = (c & 1) ? fr2 : 1.f - fr2;
                wg[ll * 8 + c] = wx * wy * wz;
            }
        }
        uint32_t val[32];
        #pragma unroll
        for (int ll = 0; ll < 4; ++ll) {
            const uint32_t* tl = tbl + (size_t)(b * 4 + ll) * (size_t)TSIZE;
            #pragma unroll
            for (int c = 0; c < 8; ++c) val[ll * 8 + c] = tl[idx[ll * 8 + c]];
        }
        #pragma unroll
        for (int ll = 0; ll < 4; ++ll) {
            float a0 = 0.f, a1 = 0.f;
            #pragma unroll
            for (int c = 0; c < 8; ++c) {
                uint32_t pv = val[ll * 8 + c];
                float w = wg[ll * 8 + c];
                a0 = fmaf(w, __uint_as_float(pv << 16), a0);
                a1 = fmaf(w, __uint_as_float(pv & 0xffff0000u), a1);
            }
            emb[2 * (b * 4 + ll)]     = a0;
            emb[2 * (b * 4 + ll) + 1] = a1;
        }
    }

    float h1[64];
    #pragma unroll
    for (int j = 0; j < 64; ++j) {
        float s = 0.f;
        #pragma unroll
        for (int k = 0; k < 32; ++k) s = fmaf(emb[k], xyz_w0[j * 32 + k], s);
        h1[j] = fmaxf(s, 0.f);
    }
    float hh[16];
    #pragma unroll
    for (int o = 0; o < 16; ++o) {
        float s = 0.f;
        #pragma unroll
        for (int k = 0; k < 64; ++k) s = fmaf(h1[k], xyz_wout[o * 64 + k], s);
        hh[o] = s;
    }
    out[i] = expf(hh[0]);

    float dx = d[3 * i + 0], dy = d[3 * i + 1], dz = d[3 * i + 2];
    float inv = rsqrtf(dx * dx + dy * dy + dz * dz);
    float X = dx * inv, Y = dy * inv, Z = dz * inv;
    float xx = X * X, yy = Y * Y, zz = Z * Z;
    float xy = X * Y, yz = Y * Z, xz = X * Z;

    float f[32];
    f[0]  = 0.28209479177387814f;
    f[1]  = -0.4886025119029199f * Y;
    f[2]  =  0.4886025119029199f * Z;
    f[3]  = -0.4886025119029199f * X;
    f[4]  =  1.0925484305920792f * xy;
    f[5]  = -1.0925484305920792f * yz;
    f[6]  =  0.31539156525252005f * (3.0f * zz - 1.0f);
    f[7]  = -1.0925484305920792f * xz;
    f[8]  =  0.5462742152960396f * (xx - yy);
    f[9]  = -0.5900435899266435f * Y * (3.0f * xx - yy);
    f[10] =  2.890611442640554f * xy * Z;
    f[11] = -0.4570457994644658f * Y * (4.0f * zz - xx - yy);
    f[12] =  0.3731763325901154f * Z * (2.0f * zz - 3.0f * xx - 3.0f * yy);
    f[13] = -0.4570457994644658f * X * (4.0f * zz - xx - yy);
    f[14] =  1.445305721320277f * Z * (xx - yy);
    f[15] = -0.5900435899266435f * X * (xx - 3.0f * yy);
    #pragma unroll
    for (int o = 0; o < 16; ++o) f[16 + o] = hh[o];

    float b1[64];
    #pragma unroll
    for (int j = 0; j < 64; ++j) {
        float s = 0.f;
        #pragma unroll
        for (int k = 0; k < 32; ++k) s = fmaf(f[k], rgb_w0[j * 32 + k], s);
        b1[j] = fmaxf(s, 0.f);
    }
    float b2[64];
    #pragma unroll
    for (int j = 0; j < 64; ++j) {
        float s = 0.f;
        #pragma unroll
        for (int k = 0; k < 64; ++k) s = fmaf(b1[k], rgb_w1[j * 64 + k], s);
        b2[j] = fmaxf(s, 0.f);
    }
    #pragma unroll
    for (int o = 0; o < 3; ++o) {
        float s = 0.f;
        #pragma unroll
        for (int k = 0; k < 64; ++k) s = fmaf(b2[k], rgb_wout[o * 64 + k], s);
        out[n + 3 * i + o] = 1.0f / (1.0f + expf(-s));
    }
}

extern "C" void kernel_launch(void* const* d_in, const int* in_sizes, int n_in,
                              void* d_out, int out_size, void* d_ws, size_t ws_size,
                              hipStream_t stream) {
    const float* x        = (const float*)d_in[0];
    const float* d        = (const float*)d_in[1];
    const float* table    = (const float*)d_in[2];
    const float* xyz_w0   = (const float*)d_in[3];
    const float* xyz_wout = (const float*)d_in[4];
    const float* rgb_w0   = (const float*)d_in[5];
    const float* rgb_w1   = (const float*)d_in[6];
    const float* rgb_wout = (const float*)d_in[7];
    float* out = (float*)d_out;

    int n = in_sizes[0] / 3;

    // resolution table in float64 exactly like numpy (level 14 = 1482.0045;
    // f32 recompute could floor to 1481 and corrupt every level-14 hash)
    ResTable rt;
    double b = std::exp((std::log(2048.0) - std::log(16.0)) / 15.0);
    for (int l = 0; l < NLEVELS; ++l)
        rt.r[l] = (float)std::floor(16.0 * std::pow(b, (double)l));

    int n_pairs = NLEVELS * TSIZE;
    int n_quads = n_pairs / 4;
    char* ws = (char*)d_ws;
    int blocks = (n + 255) / 256;

    if (ws_size >= (size_t)WS_TOTAL) {
        uint32_t* tbl16 = (uint32_t*)(ws + WS_TBL);
        uint2*    embT  = (uint2*)   (ws + WS_EMB);
        uint32_t* wf    = (uint32_t*)(ws + WS_WFRAG);
        hipLaunchKernelGGL(conv_table, dim3((n_quads + 255) / 256), dim3(256),
                           0, stream, table, tbl16, n_quads);
        hipLaunchKernelGGL(prep_wfrag, dim3(5), dim3(256), 0, stream,
                           xyz_w0, xyz_wout, rgb_w0, rgb_w1, rgb_wout, wf);
        hipLaunchKernelGGL(ngp_encode, dim3(blocks * 8), dim3(256), 0, stream,
                           x, tbl16, embT, rt, n);
        hipLaunchKernelGGL(ngp_mlp_mfma, dim3(blocks), dim3(256), 0, stream,
                           embT, d, wf, out, n);
    } else if (ws_size >= (size_t)n_pairs * 4u) {
        uint32_t* tbl16 = (uint32_t*)d_ws;
        hipLaunchKernelGGL(conv_table, dim3((n_quads + 255) / 256), dim3(256),
                           0, stream, table, tbl16, n_quads);
        hipLaunchKernelGGL(ngp_fused_bf16, dim3(blocks), dim3(256), 0, stream,
                           x, d, tbl16, xyz_w0, xyz_wout, rgb_w0, rgb_w1,
                           rgb_wout, out, rt, n);
    }
}

// Round 7
// 120.381 us; speedup vs baseline: 2.2665x; 1.0144x over previous
//
#include <hip/hip_runtime.h>
#include <cmath>
#include <cstdint>

#define NLEVELS 16
#define LOG2T 19
#define TSIZE (1u << LOG2T)
#define P1 2654435761u
#define P2 805459861u

struct ResTable { float r[NLEVELS]; };
struct D4Info  { int off1, off2, off3, total; };  // dense entry offsets (levels 1..3), total

typedef __attribute__((ext_vector_type(8))) short bf16x8;
typedef __attribute__((ext_vector_type(4))) float f32x4;

// ---- ws layout (bytes) ----
#define WS_TBL    0u           // 16*TSIZE*4 = 33,554,432  packed bf16 table (lvls 4-15 used)
#define WS_EMB    33554432u    // 8*N*8      = 16,777,216  packed bf16 emb
#define WS_WFRAG  50331648u    // 20*64*16   = 20,480
#define WS_D4     50352128u    // 119,236*16 = 1,907,776   dense corner-quad grids lvls 0-3
#define WS_TOTAL  52259904u

#define NCONVB 6144            // 12 levels * TSIZE/4 quads / 256
#define NWFB   5

__device__ inline uint16_t f32_to_bf16_rne(float f) {
    uint32_t u = __float_as_uint(f);
    uint32_t rounding = 0x7fffu + ((u >> 16) & 1u);
    return (uint16_t)((u + rounding) >> 16);
}
__device__ inline float bflo(uint32_t v) { return __uint_as_float(v << 16); }
__device__ inline float bfhi(uint32_t v) { return __uint_as_float(v & 0xffff0000u); }

// ---------------------------------------------------------------------------
// Prep (merged): conv table lvls 4-15 -> bf16 | weight MFMA frags | dense4 build
// ---------------------------------------------------------------------------
__global__ __launch_bounds__(256) void ngp_prep(
    const float* __restrict__ table,
    const float* __restrict__ xyz_w0, const float* __restrict__ xyz_wout,
    const float* __restrict__ rgb_w0, const float* __restrict__ rgb_w1,
    const float* __restrict__ rgb_wout,
    uint32_t* __restrict__ tbl16, uint32_t* __restrict__ wf,
    uint4* __restrict__ d4, ResTable res, D4Info di)
{
    int bid = blockIdx.x, tid = threadIdx.x;
    if (bid < NCONVB) {
        // ---- conv levels 4..15: one uint4 (4 packed pairs) per thread
        size_t q = (size_t)bid * 256 + tid;
        const float* src = table + 8 * (size_t)TSIZE + 8 * q;
        float4 a = *reinterpret_cast<const float4*>(src);
        float4 b = *reinterpret_cast<const float4*>(src + 4);
        uint4 r;
        r.x = (uint32_t)f32_to_bf16_rne(a.x) | ((uint32_t)f32_to_bf16_rne(a.y) << 16);
        r.y = (uint32_t)f32_to_bf16_rne(a.z) | ((uint32_t)f32_to_bf16_rne(a.w) << 16);
        r.z = (uint32_t)f32_to_bf16_rne(b.x) | ((uint32_t)f32_to_bf16_rne(b.y) << 16);
        r.w = (uint32_t)f32_to_bf16_rne(b.z) | ((uint32_t)f32_to_bf16_rne(b.w) << 16);
        *reinterpret_cast<uint4*>(tbl16 + 4 * (size_t)TSIZE + 4 * q) = r;
        return;
    }
    if (bid < NCONVB + NWFB) {
        // ---- weight MFMA B-fragments (identical feature map to A side)
        int t = (bid - NCONVB) * 256 + tid;
        if (t >= 20 * 64) return;
        int frag = t >> 6, lane = t & 63;
        int outc = lane & 15, g = lane >> 4;
        const float* W; int K, nout, tile, h;
        if (frag < 4)       { W = xyz_w0;   K = 32; nout = 64; tile = frag;             h = 0; }
        else if (frag < 6)  { W = xyz_wout; K = 64; nout = 16; tile = 0;                h = frag - 4; }
        else if (frag < 10) { W = rgb_w0;   K = 32; nout = 64; tile = frag - 6;         h = 0; }
        else if (frag < 18) { W = rgb_w1;   K = 64; nout = 64; tile = (frag - 10) >> 1; h = (frag - 10) & 1; }
        else                { W = rgb_wout; K = 64; nout = 3;  tile = 0;                h = frag - 18; }
        int out = tile * 16 + outc;
        uint32_t dws[4];
        #pragma unroll
        for (int dw = 0; dw < 4; ++dw) {
            int f0 = 32 * h + 8 * g + 2 * dw;
            uint32_t lo = (out < nout) ? f32_to_bf16_rne(W[out * K + f0])     : 0u;
            uint32_t hi = (out < nout) ? f32_to_bf16_rne(W[out * K + f0 + 1]) : 0u;
            dws[dw] = lo | (hi << 16);
        }
        uint4 r; r.x = dws[0]; r.y = dws[1]; r.z = dws[2]; r.w = dws[3];
        *reinterpret_cast<uint4*>(wf + 4 * (size_t)(frag * 64 + lane)) = r;
        return;
    }
    // ---- dense4 build for levels 0..3: entry (l,x,y,z) -> 4 hashed corners
    int idx = (bid - NCONVB - NWFB) * 256 + tid;
    if (idx >= di.total) return;
    int l, e = idx;
    if      (idx < di.off1) { l = 0; }
    else if (idx < di.off2) { l = 1; e -= di.off1; }
    else if (idx < di.off3) { l = 2; e -= di.off2; }
    else                    { l = 3; e -= di.off3; }
    int R = (int)res.r[l];
    int z = e % R; int t2 = e / R; int y = t2 % R; int X = t2 / R;
    const float* tl = table + (size_t)l * (size_t)TSIZE * 2u;
    uint32_t comp[4]; int c = 0;
    #pragma unroll
    for (int yo = 0; yo < 2; ++yo)
        #pragma unroll
        for (int zo = 0; zo < 2; ++zo) {
            uint32_t h = ((uint32_t)X ^ ((uint32_t)(y + yo) * P1)
                                      ^ ((uint32_t)(z + zo) * P2)) & (TSIZE - 1u);
            float2 v = *reinterpret_cast<const float2*>(tl + 2u * h);
            comp[c++] = (uint32_t)f32_to_bf16_rne(v.x) |
                        ((uint32_t)f32_to_bf16_rne(v.y) << 16);
        }
    uint4 r; r.x = comp[0]; r.y = comp[1]; r.z = comp[2]; r.w = comp[3];
    d4[idx] = r;
}

// ---------------------------------------------------------------------------
// Hashed-level gather (even-x uint2 pairing). Returns packed bf16 {f0,f1}.
// ---------------------------------------------------------------------------
__device__ inline uint32_t enc_hashed(const uint32_t* __restrict__ tl,
                                      float r, float xn0, float xn1, float xn2)
{
    float p0 = xn0 * r, p1 = xn1 * r, p2 = xn2 * r;
    float f0 = floorf(p0), f1 = floorf(p1), f2 = floorf(p2);
    float fr0 = p0 - f0, fr1 = p1 - f1, fr2 = p2 - f2;
    uint32_t xi0 = (uint32_t)f0, xi1 = (uint32_t)f1, xi2 = (uint32_t)f2;
    uint32_t hy0 = xi1 * P1, hy1 = (xi1 + 1u) * P1;
    uint32_t hz0 = xi2 * P2, hz1 = (xi2 + 1u) * P2;
    uint32_t base[4] = { hy0 ^ hz0, hy0 ^ hz1, hy1 ^ hz0, hy1 ^ hz1 };
    float wyz[4] = { (1.f - fr1) * (1.f - fr2), (1.f - fr1) * fr2,
                     fr1 * (1.f - fr2),         fr1 * fr2 };
    uint32_t v0[4], v1[4];
    const uint2* tl2 = reinterpret_cast<const uint2*>(tl);
    if ((xi0 & 1u) == 0u) {
        #pragma unroll
        for (int q = 0; q < 4; ++q) {
            uint32_t h0 = (xi0 ^ base[q]) & (TSIZE - 1u);
            uint2 pv = tl2[h0 >> 1];
            v0[q] = (h0 & 1u) ? pv.y : pv.x;
            v1[q] = (h0 & 1u) ? pv.x : pv.y;
        }
    } else {
        #pragma unroll
        for (int q = 0; q < 4; ++q) {
            v0[q] = tl[(xi0        ^ base[q]) & (TSIZE - 1u)];
            v1[q] = tl[((xi0 + 1u) ^ base[q]) & (TSIZE - 1u)];
        }
    }
    float a0 = 0.f, a1 = 0.f, wx0 = 1.f - fr0, wx1 = fr0;
    #pragma unroll
    for (int q = 0; q < 4; ++q) {
        float w0 = wyz[q] * wx0, w1 = wyz[q] * wx1;
        a0 = fmaf(w0, bflo(v0[q]), a0); a0 = fmaf(w1, bflo(v1[q]), a0);
        a1 = fmaf(w0, bfhi(v0[q]), a1); a1 = fmaf(w1, bfhi(v1[q]), a1);
    }
    return (uint32_t)f32_to_bf16_rne(a0) | ((uint32_t)f32_to_bf16_rne(a1) << 16);
}

// ---------------------------------------------------------------------------
// Kernel 1: hash encode. Slot pairs (L2-balanced per XCD):
//   slot<4 : {slot (dense4, 2x16B loads), 15-slot (hashed)}   <= 3.2MB
//   slot>=4: {slot (hashed), slot+4 (hashed)}                 <= 4.0MB
// ---------------------------------------------------------------------------
__global__ __launch_bounds__(256) void ngp_encode(
    const float* __restrict__ x, const uint32_t* __restrict__ tbl,
    const uint4* __restrict__ d4, uint2* __restrict__ embT,
    ResTable res, D4Info di, int n)
{
    int slot = blockIdx.x & 7;
    int i = (blockIdx.x >> 3) * 256 + threadIdx.x;
    if (i >= n) return;

    float xn0 = x[3 * i + 0] + 0.5f;
    float xn1 = x[3 * i + 1] + 0.5f;
    float xn2 = x[3 * i + 2] + 0.5f;

    uint2 o;
    if (slot < 4) {
        int highl = 15 - slot;
        // dense low level: issue 2x uint4 first
        float r = res.r[slot];
        int R = (int)r;
        float p0 = xn0 * r, p1 = xn1 * r, p2 = xn2 * r;
        float f0 = floorf(p0), f1 = floorf(p1), f2 = floorf(p2);
        float fr0 = p0 - f0, fr1 = p1 - f1, fr2 = p2 - f2;
        int xi0 = (int)f0, xi1 = (int)f1, xi2 = (int)f2;
        int off = (slot == 0) ? 0 : (slot == 1) ? di.off1 : (slot == 2) ? di.off2 : di.off3;
        const uint4* bp = d4 + off + ((size_t)xi0 * R + xi1) * R + xi2;
        uint4 A = bp[0];
        uint4 B = bp[R * R];
        // hashed high level (loads overlap with dense accumulate)
        uint32_t pk1 = enc_hashed(tbl + (size_t)highl * (size_t)TSIZE,
                                  res.r[highl], xn0, xn1, xn2);
        float wy0z0 = (1.f - fr1) * (1.f - fr2), wy0z1 = (1.f - fr1) * fr2;
        float wy1z0 = fr1 * (1.f - fr2),         wy1z1 = fr1 * fr2;
        float wx0 = 1.f - fr0, wx1 = fr0;
        float a0 = 0.f, a1 = 0.f;
        a0 = fmaf(wx0 * wy0z0, bflo(A.x), a0); a1 = fmaf(wx0 * wy0z0, bfhi(A.x), a1);
        a0 = fmaf(wx0 * wy0z1, bflo(A.y), a0); a1 = fmaf(wx0 * wy0z1, bfhi(A.y), a1);
        a0 = fmaf(wx0 * wy1z0, bflo(A.z), a0); a1 = fmaf(wx0 * wy1z0, bfhi(A.z), a1);
        a0 = fmaf(wx0 * wy1z1, bflo(A.w), a0); a1 = fmaf(wx0 * wy1z1, bfhi(A.w), a1);
        a0 = fmaf(wx1 * wy0z0, bflo(B.x), a0); a1 = fmaf(wx1 * wy0z0, bfhi(B.x), a1);
        a0 = fmaf(wx1 * wy0z1, bflo(B.y), a0); a1 = fmaf(wx1 * wy0z1, bfhi(B.y), a1);
        a0 = fmaf(wx1 * wy1z0, bflo(B.z), a0); a1 = fmaf(wx1 * wy1z0, bfhi(B.z), a1);
        a0 = fmaf(wx1 * wy1z1, bflo(B.w), a0); a1 = fmaf(wx1 * wy1z1, bfhi(B.w), a1);
        o.x = (uint32_t)f32_to_bf16_rne(a0) | ((uint32_t)f32_to_bf16_rne(a1) << 16);
        o.y = pk1;
    } else {
        int lowl = slot, highl = slot + 4;
        o.x = enc_hashed(tbl + (size_t)lowl  * (size_t)TSIZE, res.r[lowl],  xn0, xn1, xn2);
        o.y = enc_hashed(tbl + (size_t)highl * (size_t)TSIZE, res.r[highl], xn0, xn1, xn2);
    }
    embT[(size_t)slot * n + i] = o;
}

// ---------------------------------------------------------------------------
// Kernel 2: SH + MLPs via MFMA (r6 structure; high-dword remap for new slots).
// C/D layout (m89-verified): col = lane&15, row = (lane>>4)*4 + reg.
// ---------------------------------------------------------------------------
#define WF(idx) (*reinterpret_cast<const bf16x8*>(&wlds[((idx) * 64 + lane) * 4]))

#define STORE_RELU_TILE(cc, t)                                                  \
    a16[(g * 4 + 0) * 72 + (t) * 16 + outc] = f32_to_bf16_rne(fmaxf((cc)[0], 0.f)); \
    a16[(g * 4 + 1) * 72 + (t) * 16 + outc] = f32_to_bf16_rne(fmaxf((cc)[1], 0.f)); \
    a16[(g * 4 + 2) * 72 + (t) * 16 + outc] = f32_to_bf16_rne(fmaxf((cc)[2], 0.f)); \
    a16[(g * 4 + 3) * 72 + (t) * 16 + outc] = f32_to_bf16_rne(fmaxf((cc)[3], 0.f));

__global__ __launch_bounds__(256, 4) void ngp_mlp_mfma(
    const uint2* __restrict__ embT,     // (8, N) packed bf16
    const float* __restrict__ d,        // (N,3)
    const uint32_t* __restrict__ wfrag, // 20*64*4 dwords
    float* __restrict__ out, int n)
{
    __shared__ uint32_t wlds[20 * 64 * 4];
    __shared__ __attribute__((aligned(16))) uint16_t act[4][16 * 72];

    int tid = threadIdx.x;
    {
        const uint4* src = reinterpret_cast<const uint4*>(wfrag);
        uint4* dst = reinterpret_cast<uint4*>(wlds);
        #pragma unroll
        for (int k = 0; k < 5; ++k) dst[tid + 256 * k] = src[tid + 256 * k];
    }
    __syncthreads();

    int w = tid >> 6, lane = tid & 63;
    int outc = lane & 15, g = lane >> 4;
    uint16_t* a16 = act[w];
    uint32_t* a32 = reinterpret_cast<uint32_t*>(act[w]);

    const int ROUNDS = 4;
    int wave_global = blockIdx.x * 4 + w;

    for (int r = 0; r < ROUNDS; ++r) {
        int pt0 = (wave_global * ROUNDS + r) * 16;
        if (pt0 >= n) break;

        int s = lane >> 3, pp = 2 * (lane & 7);
        int hs = (s < 4) ? (15 - s) : (4 + s);   // slot high-level dword
        uint4 ev = *reinterpret_cast<const uint4*>(embT + (size_t)s * n + pt0 + pp);
        int ptd = pt0 + outc;
        float dx = d[3 * ptd + 0], dy = d[3 * ptd + 1], dz = d[3 * ptd + 2];

        a32[pp * 36 + s]        = ev.x;
        a32[pp * 36 + hs]       = ev.y;
        a32[(pp + 1) * 36 + s]  = ev.z;
        a32[(pp + 1) * 36 + hs] = ev.w;

        // ---- xyz layer 1: 32 -> 64, ReLU
        bf16x8 a0 = *reinterpret_cast<const bf16x8*>(&a16[outc * 72 + g * 8]);
        f32x4 c0 = {0.f,0.f,0.f,0.f}, c1 = {0.f,0.f,0.f,0.f};
        f32x4 c2 = {0.f,0.f,0.f,0.f}, c3 = {0.f,0.f,0.f,0.f};
        c0 = __builtin_amdgcn_mfma_f32_16x16x32_bf16(a0, WF(0), c0, 0, 0, 0);
        c1 = __builtin_amdgcn_mfma_f32_16x16x32_bf16(a0, WF(1), c1, 0, 0, 0);
        c2 = __builtin_amdgcn_mfma_f32_16x16x32_bf16(a0, WF(2), c2, 0, 0, 0);
        c3 = __builtin_amdgcn_mfma_f32_16x16x32_bf16(a0, WF(3), c3, 0, 0, 0);
        STORE_RELU_TILE(c0, 0) STORE_RELU_TILE(c1, 1)
        STORE_RELU_TILE(c2, 2) STORE_RELU_TILE(c3, 3)

        // ---- xyz layer 2: 64 -> 16 (linear)
        bf16x8 a1a = *reinterpret_cast<const bf16x8*>(&a16[outc * 72 + g * 8]);
        bf16x8 a1b = *reinterpret_cast<const bf16x8*>(&a16[outc * 72 + 32 + g * 8]);
        f32x4 ch = {0.f,0.f,0.f,0.f};
        ch = __builtin_amdgcn_mfma_f32_16x16x32_bf16(a1a, WF(4), ch, 0, 0, 0);
        ch = __builtin_amdgcn_mfma_f32_16x16x32_bf16(a1b, WF(5), ch, 0, 0, 0);

        if (outc == 0) {
            float4 sg;
            sg.x = expf(ch[0]); sg.y = expf(ch[1]);
            sg.z = expf(ch[2]); sg.w = expf(ch[3]);
            *reinterpret_cast<float4*>(out + pt0 + g * 4) = sg;
        }
        a16[(g * 4 + 0) * 72 + 16 + outc] = f32_to_bf16_rne(ch[0]);
        a16[(g * 4 + 1) * 72 + 16 + outc] = f32_to_bf16_rne(ch[1]);
        a16[(g * 4 + 2) * 72 + 16 + outc] = f32_to_bf16_rne(ch[2]);
        a16[(g * 4 + 3) * 72 + 16 + outc] = f32_to_bf16_rne(ch[3]);

        // ---- SH degree-4 into feats 0..15
        {
            float inv = rsqrtf(dx * dx + dy * dy + dz * dz);
            float X = dx * inv, Y = dy * inv, Z = dz * inv;
            float xx = X * X, yy = Y * Y, zz = Z * Z;
            float xy = X * Y, yz = Y * Z, xz = X * Z;
            float t0  = 0.28209479177387814f;
            float t1  = -0.4886025119029199f * Y;
            float t2  =  0.4886025119029199f * Z;
            float t3  = -0.4886025119029199f * X;
            float t4  =  1.0925484305920792f * xy;
            float t5  = -1.0925484305920792f * yz;
            float t6  =  0.31539156525252005f * (3.0f * zz - 1.0f);
            float t7  = -1.0925484305920792f * xz;
            float t8  =  0.5462742152960396f * (xx - yy);
            float t9  = -0.5900435899266435f * Y * (3.0f * xx - yy);
            float t10 =  2.890611442640554f * xy * Z;
            float t11 = -0.4570457994644658f * Y * (4.0f * zz - xx - yy);
            float t12 =  0.3731763325901154f * Z * (2.0f * zz - 3.0f * xx - 3.0f * yy);
            float t13 = -0.4570457994644658f * X * (4.0f * zz - xx - yy);
            float t14 =  1.445305721320277f * Z * (xx - yy);
            float t15 = -0.5900435899266435f * X * (xx - 3.0f * yy);
            float v0 = (g == 0) ? t0 : (g == 1) ? t4 : (g == 2) ? t8  : t12;
            float v1 = (g == 0) ? t1 : (g == 1) ? t5 : (g == 2) ? t9  : t13;
            float v2 = (g == 0) ? t2 : (g == 1) ? t6 : (g == 2) ? t10 : t14;
            float v3 = (g == 0) ? t3 : (g == 1) ? t7 : (g == 2) ? t11 : t15;
            uint2 pk;
            pk.x = (uint32_t)f32_to_bf16_rne(v0) | ((uint32_t)f32_to_bf16_rne(v1) << 16);
            pk.y = (uint32_t)f32_to_bf16_rne(v2) | ((uint32_t)f32_to_bf16_rne(v3) << 16);
            *reinterpret_cast<uint2*>(&a32[outc * 36 + g * 2]) = pk;
        }

        // ---- rgb layer 1: 32 -> 64, ReLU
        bf16x8 af = *reinterpret_cast<const bf16x8*>(&a16[outc * 72 + g * 8]);
        c0 = f32x4{0.f,0.f,0.f,0.f}; c1 = f32x4{0.f,0.f,0.f,0.f};
        c2 = f32x4{0.f,0.f,0.f,0.f}; c3 = f32x4{0.f,0.f,0.f,0.f};
        c0 = __builtin_amdgcn_mfma_f32_16x16x32_bf16(af, WF(6), c0, 0, 0, 0);
        c1 = __builtin_amdgcn_mfma_f32_16x16x32_bf16(af, WF(7), c1, 0, 0, 0);
        c2 = __builtin_amdgcn_mfma_f32_16x16x32_bf16(af, WF(8), c2, 0, 0, 0);
        c3 = __builtin_amdgcn_mfma_f32_16x16x32_bf16(af, WF(9), c3, 0, 0, 0);
        STORE_RELU_TILE(c0, 0) STORE_RELU_TILE(c1, 1)
        STORE_RELU_TILE(c2, 2) STORE_RELU_TILE(c3, 3)

        // ---- rgb layer 2: 64 -> 64, ReLU
        bf16x8 a2a = *reinterpret_cast<const bf16x8*>(&a16[outc * 72 + g * 8]);
        bf16x8 a2b = *reinterpret_cast<const bf16x8*>(&a16[outc * 72 + 32 + g * 8]);
        c0 = f32x4{0.f,0.f,0.f,0.f}; c1 = f32x4{0.f,0.f,0.f,0.f};
        c2 = f32x4{0.f,0.f,0.f,0.f}; c3 = f32x4{0.f,0.f,0.f,0.f};
        c0 = __builtin_amdgcn_mfma_f32_16x16x32_bf16(a2a, WF(10), c0, 0, 0, 0);
        c1 = __builtin_amdgcn_mfma_f32_16x16x32_bf16(a2a, WF(12), c1, 0, 0, 0);
        c2 = __builtin_amdgcn_mfma_f32_16x16x32_bf16(a2a, WF(14), c2, 0, 0, 0);
        c3 = __builtin_amdgcn_mfma_f32_16x16x32_bf16(a2a, WF(16), c3, 0, 0, 0);
        c0 = __builtin_amdgcn_mfma_f32_16x16x32_bf16(a2b, WF(11), c0, 0, 0, 0);
        c1 = __builtin_amdgcn_mfma_f32_16x16x32_bf16(a2b, WF(13), c1, 0, 0, 0);
        c2 = __builtin_amdgcn_mfma_f32_16x16x32_bf16(a2b, WF(15), c2, 0, 0, 0);
        c3 = __builtin_amdgcn_mfma_f32_16x16x32_bf16(a2b, WF(17), c3, 0, 0, 0);
        STORE_RELU_TILE(c0, 0) STORE_RELU_TILE(c1, 1)
        STORE_RELU_TILE(c2, 2) STORE_RELU_TILE(c3, 3)

        // ---- rgb out: 64 -> 3 (padded to 16), sigmoid
        bf16x8 a3a = *reinterpret_cast<const bf16x8*>(&a16[outc * 72 + g * 8]);
        bf16x8 a3b = *reinterpret_cast<const bf16x8*>(&a16[outc * 72 + 32 + g * 8]);
        f32x4 co = {0.f,0.f,0.f,0.f};
        co = __builtin_amdgcn_mfma_f32_16x16x32_bf16(a3a, WF(18), co, 0, 0, 0);
        co = __builtin_amdgcn_mfma_f32_16x16x32_bf16(a3b, WF(19), co, 0, 0, 0);
        if (outc < 3) {
            #pragma unroll
            for (int rr = 0; rr < 4; ++rr) {
                float v = 1.0f / (1.0f + expf(-co[rr]));
                out[n + (size_t)(pt0 + g * 4 + rr) * 3 + outc] = v;
            }
        }
    }
}

// ---------------------------------------------------------------------------
// Fallback path (ws in [33.5MB, WS_TOTAL)): full conv + round-3 fused kernel.
// ---------------------------------------------------------------------------
__global__ __launch_bounds__(256) void conv_table_full(
    const float* __restrict__ t, uint32_t* __restrict__ o, int n_quads)
{
    int i = blockIdx.x * blockDim.x + threadIdx.x;
    if (i >= n_quads) return;
    float4 a = *reinterpret_cast<const float4*>(t + 8 * (size_t)i);
    float4 b = *reinterpret_cast<const float4*>(t + 8 * (size_t)i + 4);
    uint4 r;
    r.x = (uint32_t)f32_to_bf16_rne(a.x) | ((uint32_t)f32_to_bf16_rne(a.y) << 16);
    r.y = (uint32_t)f32_to_bf16_rne(a.z) | ((uint32_t)f32_to_bf16_rne(a.w) << 16);
    r.z = (uint32_t)f32_to_bf16_rne(b.x) | ((uint32_t)f32_to_bf16_rne(b.y) << 16);
    r.w = (uint32_t)f32_to_bf16_rne(b.z) | ((uint32_t)f32_to_bf16_rne(b.w) << 16);
    *reinterpret_cast<uint4*>(o + 4 * (size_t)i) = r;
}

__global__ __launch_bounds__(256) void ngp_fused_bf16(
    const float* __restrict__ x, const float* __restrict__ d,
    const uint32_t* __restrict__ tbl,
    const float* __restrict__ xyz_w0, const float* __restrict__ xyz_wout,
    const float* __restrict__ rgb_w0, const float* __restrict__ rgb_w1,
    const float* __restrict__ rgb_wout, float* __restrict__ out,
    ResTable res, int n)
{
    int i = blockIdx.x * blockDim.x + threadIdx.x;
    if (i >= n) return;

    float xn0 = x[3 * i + 0] + 0.5f;
    float xn1 = x[3 * i + 1] + 0.5f;
    float xn2 = x[3 * i + 2] + 0.5f;

    float emb[NLEVELS * 2];
    #pragma unroll
    for (int l = 0; l < NLEVELS; ++l) {
        uint32_t pk = enc_hashed(tbl + (size_t)l * (size_t)TSIZE, res.r[l],
                                 xn0, xn1, xn2);
        emb[2 * l]     = bflo(pk);
        emb[2 * l + 1] = bfhi(pk);
    }

    float h1[64];
    #pragma unroll
    for (int j = 0; j < 64; ++j) {
        float s = 0.f;
        #pragma unroll
        for (int k = 0; k < 32; ++k) s = fmaf(emb[k], xyz_w0[j * 32 + k], s);
        h1[j] = fmaxf(s, 0.f);
    }
    float hh[16];
    #pragma unroll
    for (int o = 0; o < 16; ++o) {
        float s = 0.f;
        #pragma unroll
        for (int k = 0; k < 64; ++k) s = fmaf(h1[k], xyz_wout[o * 64 + k], s);
        hh[o] = s;
    }
    out[i] = expf(hh[0]);

    float dx = d[3 * i + 0], dy = d[3 * i + 1], dz = d[3 * i + 2];
    float inv = rsqrtf(dx * dx + dy * dy + dz * dz);
    float X = dx * inv, Y = dy * inv, Z = dz * inv;
    float xx = X * X, yy = Y * Y, zz = Z * Z;
    float xy = X * Y, yz = Y * Z, xz = X * Z;

    float f[32];
    f[0]  = 0.28209479177387814f;
    f[1]  = -0.4886025119029199f * Y;
    f[2]  =  0.4886025119029199f * Z;
    f[3]  = -0.4886025119029199f * X;
    f[4]  =  1.0925484305920792f * xy;
    f[5]  = -1.0925484305920792f * yz;
    f[6]  =  0.31539156525252005f * (3.0f * zz - 1.0f);
    f[7]  = -1.0925484305920792f * xz;
    f[8]  =  0.5462742152960396f * (xx - yy);
    f[9]  = -0.5900435899266435f * Y * (3.0f * xx - yy);
    f[10] =  2.890611442640554f * xy * Z;
    f[11] = -0.4570457994644658f * Y * (4.0f * zz - xx - yy);
    f[12] =  0.3731763325901154f * Z * (2.0f * zz - 3.0f * xx - 3.0f * yy);
    f[13] = -0.4570457994644658f * X * (4.0f * zz - xx - yy);
    f[14] =  1.445305721320277f * Z * (xx - yy);
    f[15] = -0.5900435899266435f * X * (xx - 3.0f * yy);
    #pragma unroll
    for (int o = 0; o < 16; ++o) f[16 + o] = hh[o];

    float b1[64];
    #pragma unroll
    for (int j = 0; j < 64; ++j) {
        float s = 0.f;
        #pragma unroll
        for (int k = 0; k < 32; ++k) s = fmaf(f[k], rgb_w0[j * 32 + k], s);
        b1[j] = fmaxf(s, 0.f);
    }
    float b2[64];
    #pragma unroll
    for (int j = 0; j < 64; ++j) {
        float s = 0.f;
        #pragma unroll
        for (int k = 0; k < 64; ++k) s = fmaf(b1[k], rgb_w1[j * 64 + k], s);
        b2[j] = fmaxf(s, 0.f);
    }
    #pragma unroll
    for (int o = 0; o < 3; ++o) {
        float s = 0.f;
        #pragma unroll
        for (int k = 0; k < 64; ++k) s = fmaf(b2[k], rgb_wout[o * 64 + k], s);
        out[n + 3 * i + o] = 1.0f / (1.0f + expf(-s));
    }
}

extern "C" void kernel_launch(void* const* d_in, const int* in_sizes, int n_in,
                              void* d_out, int out_size, void* d_ws, size_t ws_size,
                              hipStream_t stream) {
    const float* x        = (const float*)d_in[0];
    const float* d        = (const float*)d_in[1];
    const float* table    = (const float*)d_in[2];
    const float* xyz_w0   = (const float*)d_in[3];
    const float* xyz_wout = (const float*)d_in[4];
    const float* rgb_w0   = (const float*)d_in[5];
    const float* rgb_w1   = (const float*)d_in[6];
    const float* rgb_wout = (const float*)d_in[7];
    float* out = (float*)d_out;

    int n = in_sizes[0] / 3;

    // resolution table in float64 exactly like numpy (level 14 = 1482.0045;
    // f32 recompute could floor to 1481 and corrupt every level-14 hash)
    ResTable rt;
    double b = std::exp((std::log(2048.0) - std::log(16.0)) / 15.0);
    for (int l = 0; l < NLEVELS; ++l)
        rt.r[l] = (float)std::floor(16.0 * std::pow(b, (double)l));

    // dense4 entry offsets for levels 0..3: (R+1)*R*R entries each
    D4Info di;
    {
        int off = 0, offs[4];
        for (int l = 0; l < 4; ++l) {
            int R = (int)rt.r[l];
            offs[l] = off;
            off += (R + 1) * R * R;
        }
        di.off1 = offs[1]; di.off2 = offs[2]; di.off3 = offs[3]; di.total = off;
    }

    char* ws = (char*)d_ws;
    int blocks = (n + 255) / 256;

    if (ws_size >= (size_t)WS_TOTAL) {
        uint32_t* tbl16 = (uint32_t*)(ws + WS_TBL);
        uint2*    embT  = (uint2*)   (ws + WS_EMB);
        uint32_t* wf    = (uint32_t*)(ws + WS_WFRAG);
        uint4*    d4    = (uint4*)   (ws + WS_D4);
        int dense_blocks = (di.total + 255) / 256;
        hipLaunchKernelGGL(ngp_prep, dim3(NCONVB + NWFB + dense_blocks), dim3(256),
                           0, stream, table, xyz_w0, xyz_wout, rgb_w0, rgb_w1,
                           rgb_wout, tbl16, wf, d4, rt, di);
        hipLaunchKernelGGL(ngp_encode, dim3(blocks * 8), dim3(256), 0, stream,
                           x, tbl16, d4, embT, rt, di, n);
        hipLaunchKernelGGL(ngp_mlp_mfma, dim3(blocks), dim3(256), 0, stream,
                           embT, d, wf, out, n);
    } else if (ws_size >= (size_t)(NLEVELS * TSIZE) * 4u) {
        uint32_t* tbl16 = (uint32_t*)d_ws;
        int n_quads = NLEVELS * TSIZE / 4;
        hipLaunchKernelGGL(conv_table_full, dim3((n_quads + 255) / 256), dim3(256),
                           0, stream, table, tbl16, n_quads);
        hipLaunchKernelGGL(ngp_fused_bf16, dim3(blocks), dim3(256), 0, stream,
                           x, d, tbl16, xyz_w0, xyz_wout, rgb_w0, rgb_w1,
                           rgb_wout, out, rt, n);
    }
}

// Round 8
// 119.157 us; speedup vs baseline: 2.2898x; 1.0103x over previous
//
#include <hip/hip_runtime.h>
#include <cmath>
#include <cstdint>

#define NLEVELS 16
#define LOG2T 19
#define TSIZE (1u << LOG2T)
#define P1 2654435761u
#define P2 805459861u

struct ResTable { float r[NLEVELS]; };
struct D4Info  { int off1, off2, off3, total; };

typedef __attribute__((ext_vector_type(8))) short bf16x8;
typedef __attribute__((ext_vector_type(4))) float f32x4;

// ---- ws layout (bytes) ----
#define WS_TBL    0u           // 16*TSIZE*4 = 33,554,432  packed bf16 table (lvls 4-15 used)
#define WS_EMB    33554432u    // 8*N*8      = 16,777,216  packed bf16 emb
#define WS_WFRAG  50331648u    // 20*64*16   = 20,480
#define WS_D4     50352128u    // dense corner-quad grids lvls 0-3
#define WS_TOTAL  52259904u

#define NCONVB 6144            // 12 levels * TSIZE/4 quads / 256
#define NWFB   5

__device__ inline uint16_t f32_to_bf16_rne(float f) {
    uint32_t u = __float_as_uint(f);
    uint32_t rounding = 0x7fffu + ((u >> 16) & 1u);
    return (uint16_t)((u + rounding) >> 16);
}
__device__ inline float bflo(uint32_t v) { return __uint_as_float(v << 16); }
__device__ inline float bfhi(uint32_t v) { return __uint_as_float(v & 0xffff0000u); }
__device__ inline uint32_t packbf(float a0, float a1) {
    return (uint32_t)f32_to_bf16_rne(a0) | ((uint32_t)f32_to_bf16_rne(a1) << 16);
}

// ---------------------------------------------------------------------------
// Prep (merged): conv table lvls 4-15 -> bf16 | weight MFMA frags | dense4 build
// ---------------------------------------------------------------------------
__global__ __launch_bounds__(256) void ngp_prep(
    const float* __restrict__ table,
    const float* __restrict__ xyz_w0, const float* __restrict__ xyz_wout,
    const float* __restrict__ rgb_w0, const float* __restrict__ rgb_w1,
    const float* __restrict__ rgb_wout,
    uint32_t* __restrict__ tbl16, uint32_t* __restrict__ wf,
    uint4* __restrict__ d4, ResTable res, D4Info di)
{
    int bid = blockIdx.x, tid = threadIdx.x;
    if (bid < NCONVB) {
        size_t q = (size_t)bid * 256 + tid;
        const float* src = table + 8 * (size_t)TSIZE + 8 * q;
        float4 a = *reinterpret_cast<const float4*>(src);
        float4 b = *reinterpret_cast<const float4*>(src + 4);
        uint4 r;
        r.x = packbf(a.x, a.y);  r.y = packbf(a.z, a.w);
        r.z = packbf(b.x, b.y);  r.w = packbf(b.z, b.w);
        *reinterpret_cast<uint4*>(tbl16 + 4 * (size_t)TSIZE + 4 * q) = r;
        return;
    }
    if (bid < NCONVB + NWFB) {
        int t = (bid - NCONVB) * 256 + tid;
        if (t >= 20 * 64) return;
        int frag = t >> 6, lane = t & 63;
        int outc = lane & 15, g = lane >> 4;
        const float* W; int K, nout, tile, h;
        if (frag < 4)       { W = xyz_w0;   K = 32; nout = 64; tile = frag;             h = 0; }
        else if (frag < 6)  { W = xyz_wout; K = 64; nout = 16; tile = 0;                h = frag - 4; }
        else if (frag < 10) { W = rgb_w0;   K = 32; nout = 64; tile = frag - 6;         h = 0; }
        else if (frag < 18) { W = rgb_w1;   K = 64; nout = 64; tile = (frag - 10) >> 1; h = (frag - 10) & 1; }
        else                { W = rgb_wout; K = 64; nout = 3;  tile = 0;                h = frag - 18; }
        int out = tile * 16 + outc;
        uint32_t dws[4];
        #pragma unroll
        for (int dw = 0; dw < 4; ++dw) {
            int f0 = 32 * h + 8 * g + 2 * dw;
            uint32_t lo = (out < nout) ? f32_to_bf16_rne(W[out * K + f0])     : 0u;
            uint32_t hi = (out < nout) ? f32_to_bf16_rne(W[out * K + f0 + 1]) : 0u;
            dws[dw] = lo | (hi << 16);
        }
        uint4 r; r.x = dws[0]; r.y = dws[1]; r.z = dws[2]; r.w = dws[3];
        *reinterpret_cast<uint4*>(wf + 4 * (size_t)(frag * 64 + lane)) = r;
        return;
    }
    int idx = (bid - NCONVB - NWFB) * 256 + tid;
    if (idx >= di.total) return;
    int l, e = idx;
    if      (idx < di.off1) { l = 0; }
    else if (idx < di.off2) { l = 1; e -= di.off1; }
    else if (idx < di.off3) { l = 2; e -= di.off2; }
    else                    { l = 3; e -= di.off3; }
    int R = (int)res.r[l];
    int z = e % R; int t2 = e / R; int y = t2 % R; int X = t2 / R;
    const float* tl = table + (size_t)l * (size_t)TSIZE * 2u;
    uint32_t comp[4]; int c = 0;
    #pragma unroll
    for (int yo = 0; yo < 2; ++yo)
        #pragma unroll
        for (int zo = 0; zo < 2; ++zo) {
            uint32_t h = ((uint32_t)X ^ ((uint32_t)(y + yo) * P1)
                                      ^ ((uint32_t)(z + zo) * P2)) & (TSIZE - 1u);
            float2 v = *reinterpret_cast<const float2*>(tl + 2u * h);
            comp[c++] = packbf(v.x, v.y);
        }
    uint4 r; r.x = comp[0]; r.y = comp[1]; r.z = comp[2]; r.w = comp[3];
    d4[idx] = r;
}

// ---------------------------------------------------------------------------
// Hashed-level gather, ISSUE phase: compute addrs, issue loads, store RAW
// values + weights + parity. NO use of loaded data here (the pv.x/pv.y select
// is deferred to accumulate as a weight swap) -> no waitcnt between levels,
// all loads of all levels stay in flight together.
// ---------------------------------------------------------------------------
__device__ __forceinline__ uint32_t hashed_issue(
    const uint32_t* __restrict__ tl, float r,
    float xn0, float xn1, float xn2,
    uint32_t* __restrict__ v, float* __restrict__ w)
{
    float p0 = xn0 * r, p1 = xn1 * r, p2 = xn2 * r;
    float f0 = floorf(p0), f1 = floorf(p1), f2 = floorf(p2);
    float fr0 = p0 - f0, fr1 = p1 - f1, fr2 = p2 - f2;
    uint32_t xi0 = (uint32_t)f0, xi1 = (uint32_t)f1, xi2 = (uint32_t)f2;
    uint32_t hy0 = xi1 * P1, hy1 = (xi1 + 1u) * P1;
    uint32_t hz0 = xi2 * P2, hz1 = (xi2 + 1u) * P2;
    uint32_t base[4] = { hy0 ^ hz0, hy0 ^ hz1, hy1 ^ hz0, hy1 ^ hz1 };
    w[0] = (1.f - fr1) * (1.f - fr2);
    w[1] = (1.f - fr1) * fr2;
    w[2] = fr1 * (1.f - fr2);
    w[3] = fr1 * fr2;
    w[4] = 1.f - fr0;
    w[5] = fr0;
    uint32_t par = 0u;
    const uint2* tl2 = reinterpret_cast<const uint2*>(tl);
    if ((xi0 & 1u) == 0u) {
        #pragma unroll
        for (int q = 0; q < 4; ++q) {
            uint32_t h0 = (xi0 ^ base[q]) & (TSIZE - 1u);
            uint2 pv = tl2[h0 >> 1];          // raw: {tl[2k], tl[2k+1]}
            v[2 * q]     = pv.x;
            v[2 * q + 1] = pv.y;
            par |= (h0 & 1u) << q;
        }
    } else {
        #pragma unroll
        for (int q = 0; q < 4; ++q) {
            v[2 * q]     = tl[(xi0        ^ base[q]) & (TSIZE - 1u)];  // x0
            v[2 * q + 1] = tl[((xi0 + 1u) ^ base[q]) & (TSIZE - 1u)];  // x1
        }
    }
    return par;
}

__device__ __forceinline__ uint32_t hashed_accum(
    const uint32_t* __restrict__ v, const float* __restrict__ w, uint32_t par)
{
    float a0 = 0.f, a1 = 0.f;
    #pragma unroll
    for (int q = 0; q < 4; ++q) {
        float wq0 = w[q] * w[4], wq1 = w[q] * w[5];
        bool p = (par >> q) & 1u;          // parity: v[2q] is x1 corner
        float wa = p ? wq1 : wq0;
        float wb = p ? wq0 : wq1;
        a0 = fmaf(wa, bflo(v[2 * q]), a0); a0 = fmaf(wb, bflo(v[2 * q + 1]), a0);
        a1 = fmaf(wa, bfhi(v[2 * q]), a1); a1 = fmaf(wb, bfhi(v[2 * q + 1]), a1);
    }
    return packbf(a0, a1);
}

// ---- dense low-level (grids in ws) issue/accum ----
struct DenseCtx { uint4 A, B; float w00, w01, w10, w11, wx0, wx1; };

__device__ __forceinline__ void dense_issue(
    const uint4* __restrict__ base, int R, float r,
    float xn0, float xn1, float xn2, DenseCtx& c)
{
    float p0 = xn0 * r, p1 = xn1 * r, p2 = xn2 * r;
    float f0 = floorf(p0), f1 = floorf(p1), f2 = floorf(p2);
    float fr0 = p0 - f0, fr1 = p1 - f1, fr2 = p2 - f2;
    int xi0 = (int)f0, xi1 = (int)f1, xi2 = (int)f2;
    const uint4* bp = base + ((size_t)xi0 * R + xi1) * R + xi2;
    c.A = bp[0];
    c.B = bp[R * R];
    c.w00 = (1.f - fr1) * (1.f - fr2); c.w01 = (1.f - fr1) * fr2;
    c.w10 = fr1 * (1.f - fr2);         c.w11 = fr1 * fr2;
    c.wx0 = 1.f - fr0;                 c.wx1 = fr0;
}

__device__ __forceinline__ uint32_t dense_accum(const DenseCtx& c)
{
    float a0 = 0.f, a1 = 0.f;
    a0 = fmaf(c.wx0 * c.w00, bflo(c.A.x), a0); a1 = fmaf(c.wx0 * c.w00, bfhi(c.A.x), a1);
    a0 = fmaf(c.wx0 * c.w01, bflo(c.A.y), a0); a1 = fmaf(c.wx0 * c.w01, bfhi(c.A.y), a1);
    a0 = fmaf(c.wx0 * c.w10, bflo(c.A.z), a0); a1 = fmaf(c.wx0 * c.w10, bfhi(c.A.z), a1);
    a0 = fmaf(c.wx0 * c.w11, bflo(c.A.w), a0); a1 = fmaf(c.wx0 * c.w11, bfhi(c.A.w), a1);
    a0 = fmaf(c.wx1 * c.w00, bflo(c.B.x), a0); a1 = fmaf(c.wx1 * c.w00, bfhi(c.B.x), a1);
    a0 = fmaf(c.wx1 * c.w01, bflo(c.B.y), a0); a1 = fmaf(c.wx1 * c.w01, bfhi(c.B.y), a1);
    a0 = fmaf(c.wx1 * c.w10, bflo(c.B.z), a0); a1 = fmaf(c.wx1 * c.w10, bfhi(c.B.z), a1);
    a0 = fmaf(c.wx1 * c.w11, bflo(c.B.w), a0); a1 = fmaf(c.wx1 * c.w11, bfhi(c.B.w), a1);
    return packbf(a0, a1);
}

// ---------------------------------------------------------------------------
// Kernel 1: hash encode. 2 points per thread (stride-256 pair, coalesced);
// ALL loads of both points x both levels issued before any accumulate ->
// ~26 avg lane-addresses in flight per wave (latency-concurrency fix).
// Slot pairs unchanged: s<4 {dense s, hashed 15-s}; s>=4 {s, s+4}.
// ---------------------------------------------------------------------------
__global__ __launch_bounds__(256) void ngp_encode(
    const float* __restrict__ x, const uint32_t* __restrict__ tbl,
    const uint4* __restrict__ d4, uint2* __restrict__ embT,
    ResTable res, D4Info di, int n)
{
    int slot  = blockIdx.x & 7;
    int chunk = blockIdx.x >> 3;
    int iA = chunk * 512 + threadIdx.x;
    if (iA >= n) return;
    int iB  = iA + 256;
    int iBc = (iB < n) ? iB : (n - 1);   // clamped (safe loads, write skipped)

    float a0 = x[3 * iA + 0] + 0.5f, a1 = x[3 * iA + 1] + 0.5f, a2 = x[3 * iA + 2] + 0.5f;
    float b0 = x[3 * iBc + 0] + 0.5f, b1 = x[3 * iBc + 1] + 0.5f, b2 = x[3 * iBc + 2] + 0.5f;

    uint2 oA, oB;
    if (slot < 4) {
        int highl = 15 - slot;
        float rD = res.r[slot];
        int R = (int)rD;
        int off = (slot == 0) ? 0 : (slot == 1) ? di.off1 : (slot == 2) ? di.off2 : di.off3;
        const uint4* dbase = d4 + off;
        const uint32_t* tlh = tbl + (size_t)highl * (size_t)TSIZE;
        float rH = res.r[highl];

        DenseCtx dA, dB;
        uint32_t vA[8], vB[8]; float wA[6], wB[6];
        // issue everything
        dense_issue(dbase, R, rD, a0, a1, a2, dA);
        dense_issue(dbase, R, rD, b0, b1, b2, dB);
        uint32_t pA = hashed_issue(tlh, rH, a0, a1, a2, vA, wA);
        uint32_t pB = hashed_issue(tlh, rH, b0, b1, b2, vB, wB);
        // accumulate everything
        oA.x = dense_accum(dA); oA.y = hashed_accum(vA, wA, pA);
        oB.x = dense_accum(dB); oB.y = hashed_accum(vB, wB, pB);
    } else {
        int lowl = slot, highl = slot + 4;
        const uint32_t* tll = tbl + (size_t)lowl  * (size_t)TSIZE;
        const uint32_t* tlh = tbl + (size_t)highl * (size_t)TSIZE;
        float rL = res.r[lowl], rH = res.r[highl];

        uint32_t vA0[8], vA1[8], vB0[8], vB1[8];
        float wA0[6], wA1[6], wB0[6], wB1[6];
        // issue everything (4 level-point gathers, up to 32 loads in flight)
        uint32_t pA0 = hashed_issue(tll, rL, a0, a1, a2, vA0, wA0);
        uint32_t pA1 = hashed_issue(tlh, rH, a0, a1, a2, vA1, wA1);
        uint32_t pB0 = hashed_issue(tll, rL, b0, b1, b2, vB0, wB0);
        uint32_t pB1 = hashed_issue(tlh, rH, b0, b1, b2, vB1, wB1);
        // accumulate everything
        oA.x = hashed_accum(vA0, wA0, pA0); oA.y = hashed_accum(vA1, wA1, pA1);
        oB.x = hashed_accum(vB0, wB0, pB0); oB.y = hashed_accum(vB1, wB1, pB1);
    }
    embT[(size_t)slot * n + iA] = oA;
    if (iB < n) embT[(size_t)slot * n + iB] = oB;
}

// ---------------------------------------------------------------------------
// Kernel 2: SH + MLPs via MFMA (unchanged from r7).
// C/D layout (m89-verified): col = lane&15, row = (lane>>4)*4 + reg.
// ---------------------------------------------------------------------------
#define WF(idx) (*reinterpret_cast<const bf16x8*>(&wlds[((idx) * 64 + lane) * 4]))

#define STORE_RELU_TILE(cc, t)                                                  \
    a16[(g * 4 + 0) * 72 + (t) * 16 + outc] = f32_to_bf16_rne(fmaxf((cc)[0], 0.f)); \
    a16[(g * 4 + 1) * 72 + (t) * 16 + outc] = f32_to_bf16_rne(fmaxf((cc)[1], 0.f)); \
    a16[(g * 4 + 2) * 72 + (t) * 16 + outc] = f32_to_bf16_rne(fmaxf((cc)[2], 0.f)); \
    a16[(g * 4 + 3) * 72 + (t) * 16 + outc] = f32_to_bf16_rne(fmaxf((cc)[3], 0.f));

__global__ __launch_bounds__(256, 4) void ngp_mlp_mfma(
    const uint2* __restrict__ embT,
    const float* __restrict__ d,
    const uint32_t* __restrict__ wfrag,
    float* __restrict__ out, int n)
{
    __shared__ uint32_t wlds[20 * 64 * 4];
    __shared__ __attribute__((aligned(16))) uint16_t act[4][16 * 72];

    int tid = threadIdx.x;
    {
        const uint4* src = reinterpret_cast<const uint4*>(wfrag);
        uint4* dst = reinterpret_cast<uint4*>(wlds);
        #pragma unroll
        for (int k = 0; k < 5; ++k) dst[tid + 256 * k] = src[tid + 256 * k];
    }
    __syncthreads();

    int w = tid >> 6, lane = tid & 63;
    int outc = lane & 15, g = lane >> 4;
    uint16_t* a16 = act[w];
    uint32_t* a32 = reinterpret_cast<uint32_t*>(act[w]);

    const int ROUNDS = 4;
    int wave_global = blockIdx.x * 4 + w;

    for (int r = 0; r < ROUNDS; ++r) {
        int pt0 = (wave_global * ROUNDS + r) * 16;
        if (pt0 >= n) break;

        int s = lane >> 3, pp = 2 * (lane & 7);
        int hs = (s < 4) ? (15 - s) : (4 + s);
        uint4 ev = *reinterpret_cast<const uint4*>(embT + (size_t)s * n + pt0 + pp);
        int ptd = pt0 + outc;
        float dx = d[3 * ptd + 0], dy = d[3 * ptd + 1], dz = d[3 * ptd + 2];

        a32[pp * 36 + s]        = ev.x;
        a32[pp * 36 + hs]       = ev.y;
        a32[(pp + 1) * 36 + s]  = ev.z;
        a32[(pp + 1) * 36 + hs] = ev.w;

        bf16x8 a0 = *reinterpret_cast<const bf16x8*>(&a16[outc * 72 + g * 8]);
        f32x4 c0 = {0.f,0.f,0.f,0.f}, c1 = {0.f,0.f,0.f,0.f};
        f32x4 c2 = {0.f,0.f,0.f,0.f}, c3 = {0.f,0.f,0.f,0.f};
        c0 = __builtin_amdgcn_mfma_f32_16x16x32_bf16(a0, WF(0), c0, 0, 0, 0);
        c1 = __builtin_amdgcn_mfma_f32_16x16x32_bf16(a0, WF(1), c1, 0, 0, 0);
        c2 = __builtin_amdgcn_mfma_f32_16x16x32_bf16(a0, WF(2), c2, 0, 0, 0);
        c3 = __builtin_amdgcn_mfma_f32_16x16x32_bf16(a0, WF(3), c3, 0, 0, 0);
        STORE_RELU_TILE(c0, 0) STORE_RELU_TILE(c1, 1)
        STORE_RELU_TILE(c2, 2) STORE_RELU_TILE(c3, 3)

        bf16x8 a1a = *reinterpret_cast<const bf16x8*>(&a16[outc * 72 + g * 8]);
        bf16x8 a1b = *reinterpret_cast<const bf16x8*>(&a16[outc * 72 + 32 + g * 8]);
        f32x4 ch = {0.f,0.f,0.f,0.f};
        ch = __builtin_amdgcn_mfma_f32_16x16x32_bf16(a1a, WF(4), ch, 0, 0, 0);
        ch = __builtin_amdgcn_mfma_f32_16x16x32_bf16(a1b, WF(5), ch, 0, 0, 0);

        if (outc == 0) {
            float4 sg;
            sg.x = expf(ch[0]); sg.y = expf(ch[1]);
            sg.z = expf(ch[2]); sg.w = expf(ch[3]);
            *reinterpret_cast<float4*>(out + pt0 + g * 4) = sg;
        }
        a16[(g * 4 + 0) * 72 + 16 + outc] = f32_to_bf16_rne(ch[0]);
        a16[(g * 4 + 1) * 72 + 16 + outc] = f32_to_bf16_rne(ch[1]);
        a16[(g * 4 + 2) * 72 + 16 + outc] = f32_to_bf16_rne(ch[2]);
        a16[(g * 4 + 3) * 72 + 16 + outc] = f32_to_bf16_rne(ch[3]);

        {
            float inv = rsqrtf(dx * dx + dy * dy + dz * dz);
            float X = dx * inv, Y = dy * inv, Z = dz * inv;
            float xx = X * X, yy = Y * Y, zz = Z * Z;
            float xy = X * Y, yz = Y * Z, xz = X * Z;
            float t0  = 0.28209479177387814f;
            float t1  = -0.4886025119029199f * Y;
            float t2  =  0.4886025119029199f * Z;
            float t3  = -0.4886025119029199f * X;
            float t4  =  1.0925484305920792f * xy;
            float t5  = -1.0925484305920792f * yz;
            float t6  =  0.31539156525252005f * (3.0f * zz - 1.0f);
            float t7  = -1.0925484305920792f * xz;
            float t8  =  0.5462742152960396f * (xx - yy);
            float t9  = -0.5900435899266435f * Y * (3.0f * xx - yy);
            float t10 =  2.890611442640554f * xy * Z;
            float t11 = -0.4570457994644658f * Y * (4.0f * zz - xx - yy);
            float t12 =  0.3731763325901154f * Z * (2.0f * zz - 3.0f * xx - 3.0f * yy);
            float t13 = -0.4570457994644658f * X * (4.0f * zz - xx - yy);
            float t14 =  1.445305721320277f * Z * (xx - yy);
            float t15 = -0.5900435899266435f * X * (xx - 3.0f * yy);
            float v0 = (g == 0) ? t0 : (g == 1) ? t4 : (g == 2) ? t8  : t12;
            float v1 = (g == 0) ? t1 : (g == 1) ? t5 : (g == 2) ? t9  : t13;
            float v2 = (g == 0) ? t2 : (g == 1) ? t6 : (g == 2) ? t10 : t14;
            float v3 = (g == 0) ? t3 : (g == 1) ? t7 : (g == 2) ? t11 : t15;
            uint2 pk;
            pk.x = packbf(v0, v1);
            pk.y = packbf(v2, v3);
            *reinterpret_cast<uint2*>(&a32[outc * 36 + g * 2]) = pk;
        }

        bf16x8 af = *reinterpret_cast<const bf16x8*>(&a16[outc * 72 + g * 8]);
        c0 = f32x4{0.f,0.f,0.f,0.f}; c1 = f32x4{0.f,0.f,0.f,0.f};
        c2 = f32x4{0.f,0.f,0.f,0.f}; c3 = f32x4{0.f,0.f,0.f,0.f};
        c0 = __builtin_amdgcn_mfma_f32_16x16x32_bf16(af, WF(6), c0, 0, 0, 0);
        c1 = __builtin_amdgcn_mfma_f32_16x16x32_bf16(af, WF(7), c1, 0, 0, 0);
        c2 = __builtin_amdgcn_mfma_f32_16x16x32_bf16(af, WF(8), c2, 0, 0, 0);
        c3 = __builtin_amdgcn_mfma_f32_16x16x32_bf16(af, WF(9), c3, 0, 0, 0);
        STORE_RELU_TILE(c0, 0) STORE_RELU_TILE(c1, 1)
        STORE_RELU_TILE(c2, 2) STORE_RELU_TILE(c3, 3)

        bf16x8 a2a = *reinterpret_cast<const bf16x8*>(&a16[outc * 72 + g * 8]);
        bf16x8 a2b = *reinterpret_cast<const bf16x8*>(&a16[outc * 72 + 32 + g * 8]);
        c0 = f32x4{0.f,0.f,0.f,0.f}; c1 = f32x4{0.f,0.f,0.f,0.f};
        c2 = f32x4{0.f,0.f,0.f,0.f}; c3 = f32x4{0.f,0.f,0.f,0.f};
        c0 = __builtin_amdgcn_mfma_f32_16x16x32_bf16(a2a, WF(10), c0, 0, 0, 0);
        c1 = __builtin_amdgcn_mfma_f32_16x16x32_bf16(a2a, WF(12), c1, 0, 0, 0);
        c2 = __builtin_amdgcn_mfma_f32_16x16x32_bf16(a2a, WF(14), c2, 0, 0, 0);
        c3 = __builtin_amdgcn_mfma_f32_16x16x32_bf16(a2a, WF(16), c3, 0, 0, 0);
        c0 = __builtin_amdgcn_mfma_f32_16x16x32_bf16(a2b, WF(11), c0, 0, 0, 0);
        c1 = __builtin_amdgcn_mfma_f32_16x16x32_bf16(a2b, WF(13), c1, 0, 0, 0);
        c2 = __builtin_amdgcn_mfma_f32_16x16x32_bf16(a2b, WF(15), c2, 0, 0, 0);
        c3 = __builtin_amdgcn_mfma_f32_16x16x32_bf16(a2b, WF(17), c3, 0, 0, 0);
        STORE_RELU_TILE(c0, 0) STORE_RELU_TILE(c1, 1)
        STORE_RELU_TILE(c2, 2) STORE_RELU_TILE(c3, 3)

        bf16x8 a3a = *reinterpret_cast<const bf16x8*>(&a16[outc * 72 + g * 8]);
        bf16x8 a3b = *reinterpret_cast<const bf16x8*>(&a16[outc * 72 + 32 + g * 8]);
        f32x4 co = {0.f,0.f,0.f,0.f};
        co = __builtin_amdgcn_mfma_f32_16x16x32_bf16(a3a, WF(18), co, 0, 0, 0);
        co = __builtin_amdgcn_mfma_f32_16x16x32_bf16(a3b, WF(19), co, 0, 0, 0);
        if (outc < 3) {
            #pragma unroll
            for (int rr = 0; rr < 4; ++rr) {
                float v = 1.0f / (1.0f + expf(-co[rr]));
                out[n + (size_t)(pt0 + g * 4 + rr) * 3 + outc] = v;
            }
        }
    }
}

// ---------------------------------------------------------------------------
// Fallback path (ws in [33.5MB, WS_TOTAL)): full conv + fused bf16 kernel.
// ---------------------------------------------------------------------------
__global__ __launch_bounds__(256) void conv_table_full(
    const float* __restrict__ t, uint32_t* __restrict__ o, int n_quads)
{
    int i = blockIdx.x * blockDim.x + threadIdx.x;
    if (i >= n_quads) return;
    float4 a = *reinterpret_cast<const float4*>(t + 8 * (size_t)i);
    float4 b = *reinterpret_cast<const float4*>(t + 8 * (size_t)i + 4);
    uint4 r;
    r.x = packbf(a.x, a.y);  r.y = packbf(a.z, a.w);
    r.z = packbf(b.x, b.y);  r.w = packbf(b.z, b.w);
    *reinterpret_cast<uint4*>(o + 4 * (size_t)i) = r;
}

__global__ __launch_bounds__(256) void ngp_fused_bf16(
    const float* __restrict__ x, const float* __restrict__ d,
    const uint32_t* __restrict__ tbl,
    const float* __restrict__ xyz_w0, const float* __restrict__ xyz_wout,
    const float* __restrict__ rgb_w0, const float* __restrict__ rgb_w1,
    const float* __restrict__ rgb_wout, float* __restrict__ out,
    ResTable res, int n)
{
    int i = blockIdx.x * blockDim.x + threadIdx.x;
    if (i >= n) return;

    float xn0 = x[3 * i + 0] + 0.5f;
    float xn1 = x[3 * i + 1] + 0.5f;
    float xn2 = x[3 * i + 2] + 0.5f;

    float emb[NLEVELS * 2];
    #pragma unroll
    for (int l = 0; l < NLEVELS; ++l) {
        uint32_t v[8]; float w[6];
        uint32_t p = hashed_issue(tbl + (size_t)l * (size_t)TSIZE, res.r[l],
                                  xn0, xn1, xn2, v, w);
        uint32_t pk = hashed_accum(v, w, p);
        emb[2 * l]     = bflo(pk);
        emb[2 * l + 1] = bfhi(pk);
    }

    float h1[64];
    #pragma unroll
    for (int j = 0; j < 64; ++j) {
        float s = 0.f;
        #pragma unroll
        for (int k = 0; k < 32; ++k) s = fmaf(emb[k], xyz_w0[j * 32 + k], s);
        h1[j] = fmaxf(s, 0.f);
    }
    float hh[16];
    #pragma unroll
    for (int o = 0; o < 16; ++o) {
        float s = 0.f;
        #pragma unroll
        for (int k = 0; k < 64; ++k) s = fmaf(h1[k], xyz_wout[o * 64 + k], s);
        hh[o] = s;
    }
    out[i] = expf(hh[0]);

    float dx = d[3 * i + 0], dy = d[3 * i + 1], dz = d[3 * i + 2];
    float inv = rsqrtf(dx * dx + dy * dy + dz * dz);
    float X = dx * inv, Y = dy * inv, Z = dz * inv;
    float xx = X * X, yy = Y * Y, zz = Z * Z;
    float xy = X * Y, yz = Y * Z, xz = X * Z;

    float f[32];
    f[0]  = 0.28209479177387814f;
    f[1]  = -0.4886025119029199f * Y;
    f[2]  =  0.4886025119029199f * Z;
    f[3]  = -0.4886025119029199f * X;
    f[4]  =  1.0925484305920792f * xy;
    f[5]  = -1.0925484305920792f * yz;
    f[6]  =  0.31539156525252005f * (3.0f * zz - 1.0f);
    f[7]  = -1.0925484305920792f * xz;
    f[8]  =  0.5462742152960396f * (xx - yy);
    f[9]  = -0.5900435899266435f * Y * (3.0f * xx - yy);
    f[10] =  2.890611442640554f * xy * Z;
    f[11] = -0.4570457994644658f * Y * (4.0f * zz - xx - yy);
    f[12] =  0.3731763325901154f * Z * (2.0f * zz - 3.0f * xx - 3.0f * yy);
    f[13] = -0.4570457994644658f * X * (4.0f * zz - xx - yy);
    f[14] =  1.445305721320277f * Z * (xx - yy);
    f[15] = -0.5900435899266435f * X * (xx - 3.0f * yy);
    #pragma unroll
    for (int o = 0; o < 16; ++o) f[16 + o] = hh[o];

    float b1[64];
    #pragma unroll
    for (int j = 0; j < 64; ++j) {
        float s = 0.f;
        #pragma unroll
        for (int k = 0; k < 32; ++k) s = fmaf(f[k], rgb_w0[j * 32 + k], s);
        b1[j] = fmaxf(s, 0.f);
    }
    float b2[64];
    #pragma unroll
    for (int j = 0; j < 64; ++j) {
        float s = 0.f;
        #pragma unroll
        for (int k = 0; k < 64; ++k) s = fmaf(b1[k], rgb_w1[j * 64 + k], s);
        b2[j] = fmaxf(s, 0.f);
    }
    #pragma unroll
    for (int o = 0; o < 3; ++o) {
        float s = 0.f;
        #pragma unroll
        for (int k = 0; k < 64; ++k) s = fmaf(b2[k], rgb_wout[o * 64 + k], s);
        out[n + 3 * i + o] = 1.0f / (1.0f + expf(-s));
    }
}

extern "C" void kernel_launch(void* const* d_in, const int* in_sizes, int n_in,
                              void* d_out, int out_size, void* d_ws, size_t ws_size,
                              hipStream_t stream) {
    const float* x        = (const float*)d_in[0];
    const float* d        = (const float*)d_in[1];
    const float* table    = (const float*)d_in[2];
    const float* xyz_w0   = (const float*)d_in[3];
    const float* xyz_wout = (const float*)d_in[4];
    const float* rgb_w0   = (const float*)d_in[5];
    const float* rgb_w1   = (const float*)d_in[6];
    const float* rgb_wout = (const float*)d_in[7];
    float* out = (float*)d_out;

    int n = in_sizes[0] / 3;

    // resolution table in float64 exactly like numpy (level 14 = 1482.0045;
    // f32 recompute could floor to 1481 and corrupt every level-14 hash)
    ResTable rt;
    double b = std::exp((std::log(2048.0) - std::log(16.0)) / 15.0);
    for (int l = 0; l < NLEVELS; ++l)
        rt.r[l] = (float)std::floor(16.0 * std::pow(b, (double)l));

    D4Info di;
    {
        int off = 0, offs[4];
        for (int l = 0; l < 4; ++l) {
            int R = (int)rt.r[l];
            offs[l] = off;
            off += (R + 1) * R * R;
        }
        di.off1 = offs[1]; di.off2 = offs[2]; di.off3 = offs[3]; di.total = off;
    }

    char* ws = (char*)d_ws;
    int blocks = (n + 255) / 256;

    if (ws_size >= (size_t)WS_TOTAL) {
        uint32_t* tbl16 = (uint32_t*)(ws + WS_TBL);
        uint2*    embT  = (uint2*)   (ws + WS_EMB);
        uint32_t* wf    = (uint32_t*)(ws + WS_WFRAG);
        uint4*    d4    = (uint4*)   (ws + WS_D4);
        int dense_blocks = (di.total + 255) / 256;
        hipLaunchKernelGGL(ngp_prep, dim3(NCONVB + NWFB + dense_blocks), dim3(256),
                           0, stream, table, xyz_w0, xyz_wout, rgb_w0, rgb_w1,
                           rgb_wout, tbl16, wf, d4, rt, di);
        int enc_chunks = (n + 511) / 512;
        hipLaunchKernelGGL(ngp_encode, dim3(enc_chunks * 8), dim3(256), 0, stream,
                           x, tbl16, d4, embT, rt, di, n);
        hipLaunchKernelGGL(ngp_mlp_mfma, dim3(blocks), dim3(256), 0, stream,
                           embT, d, wf, out, n);
    } else if (ws_size >= (size_t)(NLEVELS * TSIZE) * 4u) {
        uint32_t* tbl16 = (uint32_t*)d_ws;
        int n_quads = NLEVELS * TSIZE / 4;
        hipLaunchKernelGGL(conv_table_full, dim3((n_quads + 255) / 256), dim3(256),
                           0, stream, table, tbl16, n_quads);
        hipLaunchKernelGGL(ngp_fused_bf16, dim3(blocks), dim3(256), 0, stream,
                           x, d, tbl16, xyz_w0, xyz_wout, rgb_w0, rgb_w1,
                           rgb_wout, out, rt, n);
    }
}